// Round 1
// baseline (1065.281 us; speedup 1.0000x reference)
//
#include <hip/hip_runtime.h>
#include <math.h>

#define MT 16384          // B*N rows
#define DD 768
#define AW_OFF ((size_t)8 * MT * DD)   // 100663296

typedef __attribute__((ext_vector_type(8))) short short8;
typedef __attribute__((ext_vector_type(4))) float f32x4;

static __device__ __forceinline__ unsigned short f2bf(float f) {
  unsigned u = __float_as_uint(f);
  u += 0x7fffu + ((u >> 16) & 1u);
  return (unsigned short)(u >> 16);
}
static __device__ __forceinline__ float bf2f(unsigned short h) {
  return __uint_as_float(((unsigned)h) << 16);
}

static __device__ __forceinline__ void gload_lds16(const void* g, void* l) {
  __builtin_amdgcn_global_load_lds(
      (const __attribute__((address_space(1))) void*)g,
      (__attribute__((address_space(3))) void*)l, 16, 0, 0);
}

// ---------------------------------------------------------------- transpose
// src: (4, R, C) fp32  ->  dst: (4, C, R) bf16
__global__ void transpose_cvt(const float* __restrict__ src,
                              unsigned short* __restrict__ dst,
                              int R, int C) {
  __shared__ float t[32][33];
  const int k = blockIdx.z;
  const float* s = src + (size_t)k * R * C;
  unsigned short* d = dst + (size_t)k * R * C;
  const int r0 = blockIdx.y * 32, c0 = blockIdx.x * 32;
  const int tx = threadIdx.x & 31, ty = threadIdx.x >> 5;  // 256 thr: ty 0..7
#pragma unroll
  for (int i = 0; i < 4; i++) {
    int r = ty + i * 8;
    t[r][tx] = s[(size_t)(r0 + r) * C + c0 + tx];
  }
  __syncthreads();
#pragma unroll
  for (int i = 0; i < 4; i++) {
    int cc = ty + i * 8;
    d[(size_t)(c0 + cc) * R + r0 + tx] = f2bf(t[tx][cc]);
  }
}

// ---------------------------------------------------------------- mean over N
__global__ void col_mean(const float* __restrict__ g, float* __restrict__ out) {
  const int b = blockIdx.y, ds = blockIdx.x;        // grid (6,16), 128 thr
  const int dcol = ds * 128 + threadIdx.x;
  const float* p = g + (size_t)b * 1024 * DD + dcol;
  float s = 0.f;
  for (int n = 0; n < 1024; n++) s += p[(size_t)n * DD];
  out[b * DD + dcol] = s * (1.0f / 1024.0f);
}

// ---------------------------------------------------------------- tiny MLPs
static __device__ float2 blk_sum2(float a, float b, float* red) {
  const int tid = threadIdx.x;   // blockDim == 384
  __syncthreads();
  red[tid] = a; red[512 + tid] = b;
  if (tid < 128) { red[384 + tid] = 0.f; red[512 + 384 + tid] = 0.f; }
  __syncthreads();
  for (int s = 256; s > 0; s >>= 1) {
    if (tid < s) { red[tid] += red[tid + s]; red[512 + tid] += red[512 + tid + s]; }
    __syncthreads();
  }
  return make_float2(red[0], red[512]);
}

__global__ void small_mlp(
    const float* __restrict__ gc_mean, const float* __restrict__ qf,
    const int* __restrict__ mask,
    const float* __restrict__ gp_w1, const float* __restrict__ gp_b1,
    const float* __restrict__ gp_g1, const float* __restrict__ gp_be1,
    const float* __restrict__ gp_w2, const float* __restrict__ gp_b2,
    const float* __restrict__ swp_w1, const float* __restrict__ swp_b1,
    const float* __restrict__ swp_g1, const float* __restrict__ swp_be1,
    const float* __restrict__ swp_w2, const float* __restrict__ swp_b2,
    const float* __restrict__ swp_g2, const float* __restrict__ swp_be2,
    const float* __restrict__ swp_w3, const float* __restrict__ swp_b3,
    float* __restrict__ gcc_ws, unsigned short* __restrict__ ctxs,
    unsigned short* __restrict__ ctxu, float* __restrict__ aw)
{
  __shared__ float gm[768];
  __shared__ float buf[832];
  __shared__ float tmp[384];
  __shared__ float red[1024];
  const int b = blockIdx.x, tid = threadIdx.x;

  for (int i = tid; i < 768; i += 384) gm[i] = gc_mean[b * 768 + i];
  __syncthreads();

  // gp layer1: 384 out, K=768, LN + relu
  float z = gp_b1[tid];
  for (int k = 0; k < 768; k++) z += gm[k] * gp_w1[k * 384 + tid];
  float2 s = blk_sum2(z, z * z, red);
  {
    float mean = s.x * (1.f / 384.f);
    float rinv = rsqrtf(s.y * (1.f / 384.f) - mean * mean + 1e-5f);
    float y = (z - mean) * rinv * gp_g1[tid] + gp_be1[tid];
    tmp[tid] = fmaxf(y, 0.f);
  }
  __syncthreads();

  // gp layer2: 64 out, K=384 -> gcc (no LN/act)
  if (tid < 64) {
    float g = gp_b2[tid];
    for (int k = 0; k < 384; k++) g += tmp[k] * gp_w2[k * 64 + tid];
    gcc_ws[b * 64 + tid] = g;
    float sc = (mask[b] != 0) ? 1.0f : 0.1f;
    ctxs[b * 64 + tid] = f2bf(g * sc);
    ctxu[b * 64 + tid] = f2bf(g);
    buf[tid] = g;
  }
  for (int i = tid; i < 768; i += 384) buf[64 + i] = qf[b * 768 + i];
  __syncthreads();

  // swp layer1: 256 out, K=832, LN + gelu(exact)
  float z1 = 0.f;
  if (tid < 256) {
    z1 = swp_b1[tid];
    for (int k = 0; k < 832; k++) z1 += buf[k] * swp_w1[k * 256 + tid];
  }
  s = blk_sum2(z1, z1 * z1, red);
  {
    float mean = s.x * (1.f / 256.f);
    float rinv = rsqrtf(s.y * (1.f / 256.f) - mean * mean + 1e-5f);
    if (tid < 256) {
      float y = (z1 - mean) * rinv * swp_g1[tid] + swp_be1[tid];
      tmp[tid] = 0.5f * y * (1.f + erff(y * 0.7071067811865476f));
    }
  }
  __syncthreads();

  // swp layer2: 128 out, K=256, LN + gelu
  float z2 = 0.f;
  if (tid < 128) {
    z2 = swp_b2[tid];
    for (int k = 0; k < 256; k++) z2 += tmp[k] * swp_w2[k * 128 + tid];
  }
  s = blk_sum2(z2, z2 * z2, red);
  {
    float mean = s.x * (1.f / 128.f);
    float rinv = rsqrtf(s.y * (1.f / 128.f) - mean * mean + 1e-5f);
    if (tid < 128) {
      float y = (z2 - mean) * rinv * swp_g2[tid] + swp_be2[tid];
      tmp[tid] = 0.5f * y * (1.f + erff(y * 0.7071067811865476f));
    }
  }
  __syncthreads();

  // layer3: 8 out, K=128, softmax
  if (tid < 8) {
    float z3 = swp_b3[tid];
    for (int k = 0; k < 128; k++) z3 += tmp[k] * swp_w3[k * 8 + tid];
    buf[tid] = z3;
  }
  __syncthreads();
  if (tid < 8) {
    float mx = buf[0];
    for (int k = 1; k < 8; k++) mx = fmaxf(mx, buf[k]);
    float ssum = 0.f;
    for (int k = 0; k < 8; k++) ssum += expf(buf[k] - mx);
    aw[b * 8 + tid] = expf(buf[tid] - mx) / ssum;
  }
}

// ---------------------------------------------------------------- fused GEMM
// Block: 64 rows x full 768 features. 1024 thr = 16 waves (2 m-groups x 8 f-groups),
// wave tile 32x96. K-loop double-buffered; B panel via global_load_lds from
// pre-transposed bf16 W^T; A reg-staged (fp32->bf16) or global_load_lds (bf16 h).
// Epilogue: +bias, optional LN(full row), act, write bf16 h or fp32 out.
template<int AMODE, int ACT, int DOLN, int OUTMODE, int SKIP>
__global__ __launch_bounds__(1024, 4)
void fused_gemm(const float* __restrict__ Afp,            // AMODE0: comps slice (M x 768)
                const unsigned short* __restrict__ ctx,   // AMODE0: (16 x 64) bf16
                const unsigned short* __restrict__ Abf,   // AMODE1: h (M x 768) bf16
                const unsigned short* __restrict__ wT,    // (768 x K) bf16
                int K,
                const float* __restrict__ bias,
                const float* __restrict__ gam,
                const float* __restrict__ bet,
                unsigned short* __restrict__ hout,        // OUTMODE0
                float* __restrict__ fout,                 // OUTMODE1
                const float* __restrict__ csel,           // SKIP copy source
                const int* __restrict__ mask)
{
  __shared__ __align__(16) unsigned short Bs[2][DD * 32];
  __shared__ __align__(16) unsigned short As[2][64 * 32];
  __shared__ float red[16][64][2];
  __shared__ float mv[64][2];

  const int tid = threadIdx.x;
  const int w = tid >> 6, lane = tid & 63;
  const int m0 = blockIdx.x * 64;
  const int b = m0 >> 10;

  if (SKIP && mask[b] == 0) {
    if (OUTMODE == 1) {
      const float4* src = (const float4*)(csel + (size_t)m0 * DD);
      float4* dst = (float4*)(fout + (size_t)m0 * DD);
      for (int i = tid; i < 64 * DD / 4; i += 1024) dst[i] = src[i];
    }
    return;
  }

  f32x4 acc[2][6];
#pragma unroll
  for (int mf = 0; mf < 2; mf++)
#pragma unroll
    for (int n = 0; n < 6; n++) acc[mf][n] = (f32x4)0.0f;

  const int nkt = K >> 5;
  const int arow = tid >> 4, acol = (tid & 15) << 1;

  auto issueB = [&](int kt, int nb) {
#pragma unroll
    for (int j = 0; j < 3; j++) {
      int linear = (w * 3 + j) * 64 + lane;     // 0..3071
      int f = linear >> 2;
      int koff = (linear & 3) << 3;
      gload_lds16(wT + (size_t)f * K + kt * 32 + koff, &Bs[nb][(w * 3 + j) * 512]);
    }
  };
  auto issueA1 = [&](int kt, int nb) {
    if (w < 4) {
      int linear = (w << 6) + lane;             // 0..255
      int row = linear >> 2;
      int koff = (linear & 3) << 3;
      gload_lds16(Abf + (size_t)(m0 + row) * DD + kt * 32 + koff, &As[nb][w * 512]);
    }
  };
  auto loadA0 = [&](int kt) -> float2 {
    if (kt < 24) {
      return *(const float2*)(Afp + (size_t)(m0 + arow) * DD + kt * 32 + acol);
    } else {
      int cb = b * 64 + (kt - 24) * 32 + acol;
      return make_float2(bf2f(ctx[cb]), bf2f(ctx[cb + 1]));
    }
  };
  auto storeA0 = [&](float2 v, int nb) {
    unsigned pk = ((unsigned)f2bf(v.y) << 16) | (unsigned)f2bf(v.x);
    *(unsigned*)&As[nb][arow * 32 + acol] = pk;
  };

  const int wf0 = (w & 7) * 96;
  const int wm = w >> 3;
  const int lhi = lane >> 4, llo = lane & 15;

  auto compute = [&](int cb) {
    short8 af[2];
#pragma unroll
    for (int mf = 0; mf < 2; mf++)
      af[mf] = *(const short8*)&As[cb][(wm * 32 + mf * 16 + llo) * 32 + lhi * 8];
#pragma unroll
    for (int n = 0; n < 6; n++) {
      short8 bfr = *(const short8*)&Bs[cb][(wf0 + n * 16 + llo) * 32 + lhi * 8];
      acc[0][n] = __builtin_amdgcn_mfma_f32_16x16x32_bf16(af[0], bfr, acc[0][n], 0, 0, 0);
      acc[1][n] = __builtin_amdgcn_mfma_f32_16x16x32_bf16(af[1], bfr, acc[1][n], 0, 0, 0);
    }
  };

  // prologue: stage tile 0
  issueB(0, 0);
  if (AMODE == 0) storeA0(loadA0(0), 0); else issueA1(0, 0);
  __syncthreads();

  for (int kt = 0; kt < nkt; kt++) {
    const int cur = kt & 1, nxt = cur ^ 1;
    float2 av = make_float2(0.f, 0.f);
    bool pend = false;
    if (kt + 1 < nkt) {
      issueB(kt + 1, nxt);                       // async loads fly under MFMA
      if (AMODE == 0) { av = loadA0(kt + 1); pend = true; }
      else issueA1(kt + 1, nxt);
    }
    compute(cur);
    if (AMODE == 0 && pend) storeA0(av, nxt);    // write-late (T14)
    __syncthreads();
  }

  // ---------------- epilogue ----------------
  float bia[6], gv[6], bev[6];
#pragma unroll
  for (int n = 0; n < 6; n++) {
    int f = wf0 + n * 16 + llo;
    bia[n] = bias[f];
    if (DOLN) { gv[n] = gam[f]; bev[n] = bet[f]; }
  }

  if (DOLN) {
#pragma unroll
    for (int mf = 0; mf < 2; mf++) {
#pragma unroll
      for (int r = 0; r < 4; r++) {
        float s1 = 0.f, s2 = 0.f;
#pragma unroll
        for (int n = 0; n < 6; n++) {
          float v = acc[mf][n][r] + bia[n];
          s1 += v; s2 += v * v;
        }
#pragma unroll
        for (int d = 1; d < 16; d <<= 1) {
          s1 += __shfl_xor(s1, d);
          s2 += __shfl_xor(s2, d);
        }
        if (llo == 0) {
          int row = wm * 32 + mf * 16 + lhi * 4 + r;
          red[w][row][0] = s1;
          red[w][row][1] = s2;
        }
      }
    }
    __syncthreads();
    if (tid < 64) {
      int wmg = tid >> 5;
      float s1 = 0.f, s2 = 0.f;
#pragma unroll
      for (int i = 0; i < 8; i++) {
        s1 += red[wmg * 8 + i][tid][0];
        s2 += red[wmg * 8 + i][tid][1];
      }
      float mean = s1 * (1.f / 768.f);
      float var = s2 * (1.f / 768.f) - mean * mean;
      mv[tid][0] = mean;
      mv[tid][1] = rsqrtf(var + 1e-5f);
    }
    __syncthreads();
  }

#pragma unroll
  for (int mf = 0; mf < 2; mf++) {
#pragma unroll
    for (int r = 0; r < 4; r++) {
      const int row = wm * 32 + mf * 16 + lhi * 4 + r;
      float mean = 0.f, rinv = 0.f;
      if (DOLN) { mean = mv[row][0]; rinv = mv[row][1]; }
      const size_t rowoff = (size_t)(m0 + row) * DD;
#pragma unroll
      for (int n = 0; n < 6; n++) {
        const int f = wf0 + n * 16 + llo;
        float v = acc[mf][n][r] + bia[n];
        if (DOLN) v = (v - mean) * rinv * gv[n] + bev[n];
        if (ACT == 1) v = fmaxf(v, 0.f);
        else if (ACT == 2) v = 0.5f * v * (1.f + erff(v * 0.7071067811865476f));
        if (OUTMODE == 0) hout[rowoff + f] = f2bf(v);
        else fout[rowoff + f] = v;
      }
    }
  }
}

// ---------------------------------------------------------------- launch
extern "C" void kernel_launch(void* const* d_in, const int* in_sizes, int n_in,
                              void* d_out, int out_size, void* d_ws, size_t ws_size,
                              hipStream_t stream)
{
  (void)in_sizes; (void)n_in; (void)out_size; (void)ws_size;
  const float* comps  = (const float*)d_in[0];
  const float* geo    = (const float*)d_in[1];
  const float* qf     = (const float*)d_in[2];
  const int*   mask   = (const int*)d_in[3];
  const float* gp_w1  = (const float*)d_in[4];
  const float* gp_b1  = (const float*)d_in[5];
  const float* gp_g1  = (const float*)d_in[6];
  const float* gp_be1 = (const float*)d_in[7];
  const float* gp_w2  = (const float*)d_in[8];
  const float* gp_b2  = (const float*)d_in[9];
  const float* swp_w1 = (const float*)d_in[10];
  const float* swp_b1 = (const float*)d_in[11];
  const float* swp_g1 = (const float*)d_in[12];
  const float* swp_be1= (const float*)d_in[13];
  const float* swp_w2 = (const float*)d_in[14];
  const float* swp_b2 = (const float*)d_in[15];
  const float* swp_g2 = (const float*)d_in[16];
  const float* swp_be2= (const float*)d_in[17];
  const float* swp_w3 = (const float*)d_in[18];
  const float* swp_b3 = (const float*)d_in[19];
  const float* sw1 = (const float*)d_in[20];
  const float* sb1 = (const float*)d_in[21];
  const float* sg1 = (const float*)d_in[22];
  const float* sbe1= (const float*)d_in[23];
  const float* sw2 = (const float*)d_in[24];
  const float* sb2 = (const float*)d_in[25];
  const float* sg2 = (const float*)d_in[26];
  const float* sbe2= (const float*)d_in[27];
  const float* rw1 = (const float*)d_in[28];
  const float* rb1 = (const float*)d_in[29];
  const float* rg1 = (const float*)d_in[30];
  const float* rbe1= (const float*)d_in[31];
  const float* rw2 = (const float*)d_in[32];
  const float* rb2 = (const float*)d_in[33];
  float* out = (float*)d_out;

  char* ws = (char*)d_ws;
  float* gc_mean       = (float*)(ws + 0);                 //  48 KB
  float* gcc           = (float*)(ws + 49152);             //   4 KB
  unsigned short* cxs  = (unsigned short*)(ws + 53248);    //   2 KB
  unsigned short* cxu  = (unsigned short*)(ws + 55296);    //   2 KB
  unsigned short* s1t  = (unsigned short*)(ws + 65536);    // 4x768x832 bf16
  unsigned short* r1t  = (unsigned short*)(ws + 5177344);
  unsigned short* s2t  = (unsigned short*)(ws + 10289152); // 4x768x768 bf16
  unsigned short* r2t  = (unsigned short*)(ws + 15007744);
  unsigned short* hbuf = (unsigned short*)(ws + 19726336); // 16384x768 bf16

  transpose_cvt<<<dim3(24, 26, 4), 256, 0, stream>>>(sw1, s1t, 832, 768);
  transpose_cvt<<<dim3(24, 24, 4), 256, 0, stream>>>(sw2, s2t, 768, 768);
  transpose_cvt<<<dim3(24, 26, 4), 256, 0, stream>>>(rw1, r1t, 832, 768);
  transpose_cvt<<<dim3(24, 24, 4), 256, 0, stream>>>(rw2, r2t, 768, 768);
  col_mean<<<dim3(6, 16), 128, 0, stream>>>(geo, gc_mean);
  small_mlp<<<16, 384, 0, stream>>>(gc_mean, qf, mask,
      gp_w1, gp_b1, gp_g1, gp_be1, gp_w2, gp_b2,
      swp_w1, swp_b1, swp_g1, swp_be1, swp_w2, swp_b2, swp_g2, swp_be2,
      swp_w3, swp_b3, gcc, cxs, cxu, out + AW_OFF);

  const int cis[4] = {0, 1, 3, 5};
  const int cir[4] = {4, 2, 6, 7};

  for (int k = 0; k < 4; k++) {
    int ci = cis[k];
    // s GEMM1: comps+ctx_s -> LN -> gelu -> h
    fused_gemm<0, 2, 1, 0, 0><<<256, 1024, 0, stream>>>(
        comps + (size_t)ci * MT * DD, cxs, nullptr,
        s1t + (size_t)k * DD * 832, 832,
        sb1 + k * DD, sg1 + k * DD, sbe1 + k * DD,
        hbuf, nullptr, nullptr, mask);
    // s GEMM2: h -> LN -> out
    fused_gemm<1, 0, 1, 1, 0><<<256, 1024, 0, stream>>>(
        nullptr, nullptr, hbuf,
        s2t + (size_t)k * DD * DD, 768,
        sb2 + k * DD, sg2 + k * DD, sbe2 + k * DD,
        nullptr, out + (size_t)ci * MT * DD, nullptr, mask);
  }
  for (int k = 0; k < 4; k++) {
    int ci = cir[k];
    const unsigned short* cx = (k == 0) ? cxs : cxu;
    if (k == 0) {
      fused_gemm<0, 1, 1, 0, 0><<<256, 1024, 0, stream>>>(
          comps + (size_t)ci * MT * DD, cx, nullptr,
          r1t + (size_t)k * DD * 832, 832,
          rb1 + k * DD, rg1 + k * DD, rbe1 + k * DD,
          hbuf, nullptr, nullptr, mask);
      fused_gemm<1, 0, 0, 1, 0><<<256, 1024, 0, stream>>>(
          nullptr, nullptr, hbuf,
          r2t + (size_t)k * DD * DD, 768,
          rb2 + k * DD, nullptr, nullptr,
          nullptr, out + (size_t)ci * MT * DD, nullptr, mask);
    } else {
      fused_gemm<0, 1, 1, 0, 1><<<256, 1024, 0, stream>>>(
          comps + (size_t)ci * MT * DD, cx, nullptr,
          r1t + (size_t)k * DD * 832, 832,
          rb1 + k * DD, rg1 + k * DD, rbe1 + k * DD,
          hbuf, nullptr, nullptr, mask);
      fused_gemm<1, 0, 0, 1, 1><<<256, 1024, 0, stream>>>(
          nullptr, nullptr, hbuf,
          r2t + (size_t)k * DD * DD, 768,
          rb2 + k * DD, nullptr, nullptr,
          nullptr, out + (size_t)ci * MT * DD,
          comps + (size_t)ci * MT * DD, mask);
    }
  }
}

// Round 2
// 1045.228 us; speedup vs baseline: 1.0192x; 1.0192x over previous
//
#include <hip/hip_runtime.h>
#include <math.h>

#define MT 16384          // B*N rows
#define DD 768
#define AW_OFF ((size_t)8 * MT * DD)
#define HB_SZ  ((size_t)MT * DD * 2)
#define WS_WBASE 65536
#define WS_HBASE 19726336

typedef __attribute__((ext_vector_type(8))) short short8;
typedef __attribute__((ext_vector_type(4))) float f32x4;

static __device__ __forceinline__ unsigned short f2bf(float f) {
  unsigned u = __float_as_uint(f);
  u += 0x7fffu + ((u >> 16) & 1u);
  return (unsigned short)(u >> 16);
}

static __device__ __forceinline__ void gload_lds16(const void* g, void* l) {
  __builtin_amdgcn_global_load_lds(
      (const __attribute__((address_space(1))) void*)g,
      (__attribute__((address_space(3))) void*)l, 16, 0, 0);
}

// ---------------------------------------------------------------- transpose
// 4 weights in one dispatch. src (4,R,768) fp32 -> dst (4,768,R) bf16.
struct TArgs { const float* s[4]; unsigned short* d[4]; int R[4]; };

__global__ void transpose_cvt(TArgs a) {
  __shared__ float t[32][33];
  const int z = blockIdx.z, wsel = z >> 2, k = z & 3;
  const int R = a.R[wsel];
  const int r0 = blockIdx.y * 32, c0 = blockIdx.x * 32;
  if (r0 >= R) return;
  const float* s = a.s[wsel] + (size_t)k * R * DD;
  unsigned short* d = a.d[wsel] + (size_t)k * R * DD;
  const int tx = threadIdx.x & 31, ty = threadIdx.x >> 5;
#pragma unroll
  for (int i = 0; i < 4; i++) {
    int r = ty + i * 8;
    t[r][tx] = s[(size_t)(r0 + r) * DD + c0 + tx];
  }
  __syncthreads();
#pragma unroll
  for (int i = 0; i < 4; i++) {
    int cc = ty + i * 8;
    d[(size_t)(c0 + cc) * R + r0 + tx] = f2bf(t[tx][cc]);
  }
}

// ---------------------------------------------------------------- mean over N
__global__ void col_mean(const float* __restrict__ g, float* __restrict__ out) {
  const int b = blockIdx.y, ds = blockIdx.x;
  const int dcol = ds * 128 + threadIdx.x;
  const float* p = g + (size_t)b * 1024 * DD + dcol;
  float s = 0.f;
  for (int n = 0; n < 1024; n++) s += p[(size_t)n * DD];
  out[b * DD + dcol] = s * (1.0f / 1024.0f);
}

// ---------------------------------------------------------------- tiny MLPs
static __device__ float2 blk_sum2(float a, float b, float* red) {
  const int tid = threadIdx.x;   // blockDim == 384
  __syncthreads();
  red[tid] = a; red[512 + tid] = b;
  if (tid < 128) { red[384 + tid] = 0.f; red[512 + 384 + tid] = 0.f; }
  __syncthreads();
  for (int s = 256; s > 0; s >>= 1) {
    if (tid < s) { red[tid] += red[tid + s]; red[512 + tid] += red[512 + tid + s]; }
    __syncthreads();
  }
  return make_float2(red[0], red[512]);
}

__global__ void small_mlp(
    const float* __restrict__ gc_mean, const float* __restrict__ qf,
    const int* __restrict__ mask,
    const float* __restrict__ gp_w1, const float* __restrict__ gp_b1,
    const float* __restrict__ gp_g1, const float* __restrict__ gp_be1,
    const float* __restrict__ gp_w2, const float* __restrict__ gp_b2,
    const float* __restrict__ swp_w1, const float* __restrict__ swp_b1,
    const float* __restrict__ swp_g1, const float* __restrict__ swp_be1,
    const float* __restrict__ swp_w2, const float* __restrict__ swp_b2,
    const float* __restrict__ swp_g2, const float* __restrict__ swp_be2,
    const float* __restrict__ swp_w3, const float* __restrict__ swp_b3,
    unsigned short* __restrict__ ctxs, unsigned short* __restrict__ ctxu,
    float* __restrict__ aw)
{
  __shared__ float gm[768];
  __shared__ float buf[832];
  __shared__ float tmp[384];
  __shared__ float red[1024];
  const int b = blockIdx.x, tid = threadIdx.x;

  for (int i = tid; i < 768; i += 384) gm[i] = gc_mean[b * 768 + i];
  __syncthreads();

  float z = gp_b1[tid];
  for (int k = 0; k < 768; k++) z += gm[k] * gp_w1[k * 384 + tid];
  float2 s = blk_sum2(z, z * z, red);
  {
    float mean = s.x * (1.f / 384.f);
    float rinv = rsqrtf(s.y * (1.f / 384.f) - mean * mean + 1e-5f);
    float y = (z - mean) * rinv * gp_g1[tid] + gp_be1[tid];
    tmp[tid] = fmaxf(y, 0.f);
  }
  __syncthreads();

  if (tid < 64) {
    float g = gp_b2[tid];
    for (int k = 0; k < 384; k++) g += tmp[k] * gp_w2[k * 64 + tid];
    float sc = (mask[b] != 0) ? 1.0f : 0.1f;
    ctxs[b * 64 + tid] = f2bf(g * sc);
    ctxu[b * 64 + tid] = f2bf(g);
    buf[tid] = g;
  }
  for (int i = tid; i < 768; i += 384) buf[64 + i] = qf[b * 768 + i];
  __syncthreads();

  float z1 = 0.f;
  if (tid < 256) {
    z1 = swp_b1[tid];
    for (int k = 0; k < 832; k++) z1 += buf[k] * swp_w1[k * 256 + tid];
  }
  s = blk_sum2(z1, z1 * z1, red);
  {
    float mean = s.x * (1.f / 256.f);
    float rinv = rsqrtf(s.y * (1.f / 256.f) - mean * mean + 1e-5f);
    if (tid < 256) {
      float y = (z1 - mean) * rinv * swp_g1[tid] + swp_be1[tid];
      tmp[tid] = 0.5f * y * (1.f + erff(y * 0.7071067811865476f));
    }
  }
  __syncthreads();

  float z2 = 0.f;
  if (tid < 128) {
    z2 = swp_b2[tid];
    for (int k = 0; k < 256; k++) z2 += tmp[k] * swp_w2[k * 128 + tid];
  }
  s = blk_sum2(z2, z2 * z2, red);
  {
    float mean = s.x * (1.f / 128.f);
    float rinv = rsqrtf(s.y * (1.f / 128.f) - mean * mean + 1e-5f);
    if (tid < 128) {
      float y = (z2 - mean) * rinv * swp_g2[tid] + swp_be2[tid];
      tmp[tid] = 0.5f * y * (1.f + erff(y * 0.7071067811865476f));
    }
  }
  __syncthreads();

  if (tid < 8) {
    float z3 = swp_b3[tid];
    for (int k = 0; k < 128; k++) z3 += tmp[k] * swp_w3[k * 8 + tid];
    buf[tid] = z3;
  }
  __syncthreads();
  if (tid < 8) {
    float mx = buf[0];
    for (int k = 1; k < 8; k++) mx = fmaxf(mx, buf[k]);
    float ssum = 0.f;
    for (int k = 0; k < 8; k++) ssum += expf(buf[k] - mx);
    aw[b * 8 + tid] = expf(buf[tid] - mx) / ssum;
  }
}

// ---------------------------------------------------------------- fused GEMM
// Block: 64 rows x 768 features, 16 waves, wave-tile 64x48 (4m x 3n frags).
// LDS XOR-swizzled tiles (unit=16B: slot = f*4 + (o ^ (f&3))), staged via
// global_load_lds with pre-swizzled per-lane SOURCE (rule #21).
// Counted-vmcnt pipeline: s_waitcnt vmcnt(4) (never 0 mid-loop), raw barriers.
struct BrCfg {
  const float* Afp;
  const unsigned short* Abf;
  const unsigned short* ctx;
  const unsigned short* wT;
  const float* bias; const float* gam; const float* bet;
  unsigned short* hout;
  float* fout;
  const float* csel;
  int act;    // 0 none, 1 relu, 2 gelu
  int doln;
  int skip;
};
struct PhaseArgs { BrCfg c[8]; int gsz; };

template<int AMODE>
__global__ __launch_bounds__(1024, 4)
void gemm_phase(PhaseArgs pa, const int* __restrict__ mask)
{
  constexpr int KK  = (AMODE == 0) ? 832 : 768;
  constexpr int NKT = KK / 32;

  __shared__ __align__(16) unsigned short Bs[2][DD * 32];  // 96 KB
  __shared__ __align__(16) unsigned short As[2][64 * 32];  //  8 KB
  __shared__ float red[16][64][2];                          //  8 KB
  __shared__ float mv[64][2];

  const int gsz = pa.gsz;
  const int br  = blockIdx.x % gsz;
  const int mt  = blockIdx.x / gsz;
  const BrCfg C = pa.c[br];
  const int m0  = mt * 64;
  const int b   = mt >> 4;
  const int tid = threadIdx.x;
  const int w = tid >> 6, lane = tid & 63, llo = lane & 15, lhi = lane >> 4;
  const int wf0 = w * 48;

  if (C.skip && mask[b] == 0) {
    if (AMODE == 1) {
      const float4* s = (const float4*)(C.csel + (size_t)m0 * DD);
      float4* d = (float4*)(C.fout + (size_t)m0 * DD);
      for (int i = tid; i < 64 * DD / 4; i += 1024) d[i] = s[i];
    }
    return;
  }

  f32x4 acc[4][3];
#pragma unroll
  for (int mf = 0; mf < 4; mf++)
#pragma unroll
    for (int n = 0; n < 3; n++) acc[mf][n] = (f32x4)0.0f;

  // --- read offsets (swizzled): slot(f,o) = f*32 + ((o ^ (f&3))*8) ushorts
  int aoffs[4], boffs[3];
#pragma unroll
  for (int mf = 0; mf < 4; mf++) {
    int row = mf * 16 + llo;
    aoffs[mf] = row * 32 + ((lhi ^ (row & 3)) << 3);
  }
#pragma unroll
  for (int n = 0; n < 3; n++) {
    int f = wf0 + n * 16 + llo;
    boffs[n] = f * 32 + ((lhi ^ (f & 3)) << 3);
  }

  // --- staging sources (pre-swizzled per-lane global addresses)
  const int swo = (lane & 3) ^ ((lane >> 2) & 3);   // o for my lane slot
  const unsigned short* bsrc[3];
#pragma unroll
  for (int j = 0; j < 3; j++) {
    int c = w * 3 + j;
    int f = c * 16 + (lane >> 2);
    bsrc[j] = C.wT + (size_t)f * KK + swo * 8;
  }
  const unsigned short* a1src = nullptr;
  if (AMODE == 1 && w < 4) {
    int row = w * 16 + (lane >> 2);
    a1src = C.Abf + (size_t)(m0 + row) * DD + swo * 8;
  }
  const int arow = tid >> 4, ap = tid & 15;
  const float* a0src = nullptr;
  const unsigned short* ctxsrc = nullptr;
  if (AMODE == 0) {
    a0src = C.Afp + (size_t)(m0 + arow) * DD + ap * 2;
    ctxsrc = C.ctx + b * 64 + ap * 2;
  }

  auto issueB = [&](int kt, int nb) {
#pragma unroll
    for (int j = 0; j < 3; j++)
      gload_lds16(bsrc[j] + (size_t)kt * 32, &Bs[nb][(w * 3 + j) * 512]);
  };
  auto issueA1 = [&](int kt, int nb) {
    if (w < 4) gload_lds16(a1src + (size_t)kt * 32, &As[nb][w * 512]);
  };
  auto storeA0 = [&](unsigned pk, int nb) {
    *(unsigned*)&As[nb][arow * 32 + ((((ap >> 2) ^ (arow & 3))) << 3) + ((ap & 3) << 1)] = pk;
  };

  auto compute = [&](int cb) {
    short8 afr[4];
#pragma unroll
    for (int mf = 0; mf < 4; mf++)
      afr[mf] = *(const short8*)&As[cb][aoffs[mf]];
#pragma unroll
    for (int n = 0; n < 3; n++) {
      short8 bfr = *(const short8*)&Bs[cb][boffs[n]];
#pragma unroll
      for (int mf = 0; mf < 4; mf++)
        acc[mf][n] = __builtin_amdgcn_mfma_f32_16x16x32_bf16(afr[mf], bfr, acc[mf][n], 0, 0, 0);
    }
  };

  // ---------------- prologue: stage tile 0
  if (AMODE == 0) {
    float2 v = *(const float2*)(a0src);         // kt=0 always comps region
    issueB(0, 0);
    unsigned pk = ((unsigned)f2bf(v.y) << 16) | (unsigned)f2bf(v.x);
    storeA0(pk, 0);
  } else {
    issueA1(0, 0);
    issueB(0, 0);
  }
  asm volatile("s_waitcnt lgkmcnt(0)" ::: "memory");
  __builtin_amdgcn_sched_barrier(0);

#pragma unroll 1
  for (int kt = 0; kt < NKT; kt++) {
    const int cur = kt & 1, nxt = cur ^ 1;
    float2 araw = make_float2(0.f, 0.f);
    unsigned actx = 0;
    bool isctx = false;
    __builtin_amdgcn_sched_barrier(0);
    if (kt + 1 < NKT) {
      if (AMODE == 0) {
        if (kt + 1 < 24) araw = *(const float2*)(a0src + (kt + 1) * 32);
        else { actx = *(const unsigned*)(ctxsrc + (kt + 1 - 24) * 32); isctx = true; }
      } else {
        issueA1(kt + 1, nxt);
      }
      issueB(kt + 1, nxt);
      __builtin_amdgcn_sched_barrier(0);
      if (AMODE == 0) {
        asm volatile("s_waitcnt vmcnt(4)" ::: "memory");
      } else {
        if (w < 4) asm volatile("s_waitcnt vmcnt(4)" ::: "memory");
        else       asm volatile("s_waitcnt vmcnt(3)" ::: "memory");
      }
    } else {
      asm volatile("s_waitcnt vmcnt(0)" ::: "memory");
    }
    __builtin_amdgcn_sched_barrier(0);
    __builtin_amdgcn_s_barrier();
    compute(cur);
    if (AMODE == 0 && kt + 1 < NKT) {
      unsigned pk = isctx ? actx
                          : (((unsigned)f2bf(araw.y) << 16) | (unsigned)f2bf(araw.x));
      storeA0(pk, nxt);
    }
    asm volatile("s_waitcnt lgkmcnt(0)" ::: "memory");
    __builtin_amdgcn_sched_barrier(0);
    __builtin_amdgcn_s_barrier();
  }

  // ---------------- epilogue ----------------
  float bia[3], gv[3], bev[3];
#pragma unroll
  for (int n = 0; n < 3; n++) {
    int f = wf0 + n * 16 + llo;
    bia[n] = C.bias[f];
    if (C.doln) { gv[n] = C.gam[f]; bev[n] = C.bet[f]; }
  }

  if (C.doln) {
#pragma unroll
    for (int mf = 0; mf < 4; mf++) {
#pragma unroll
      for (int r = 0; r < 4; r++) {
        float s1 = 0.f, s2 = 0.f;
#pragma unroll
        for (int n = 0; n < 3; n++) {
          float v = acc[mf][n][r] + bia[n];
          s1 += v; s2 += v * v;
        }
#pragma unroll
        for (int d = 1; d < 16; d <<= 1) {
          s1 += __shfl_xor(s1, d);
          s2 += __shfl_xor(s2, d);
        }
        if (llo == 0) {
          int row = mf * 16 + lhi * 4 + r;
          red[w][row][0] = s1;
          red[w][row][1] = s2;
        }
      }
    }
    __syncthreads();
    if (tid < 64) {
      float s1 = 0.f, s2 = 0.f;
#pragma unroll
      for (int i = 0; i < 16; i++) { s1 += red[i][tid][0]; s2 += red[i][tid][1]; }
      float mean = s1 * (1.f / 768.f);
      float var  = s2 * (1.f / 768.f) - mean * mean;
      mv[tid][0] = mean;
      mv[tid][1] = rsqrtf(var + 1e-5f);
    }
    __syncthreads();
  }

#pragma unroll
  for (int mf = 0; mf < 4; mf++) {
#pragma unroll
    for (int r = 0; r < 4; r++) {
      const int row = mf * 16 + lhi * 4 + r;
      float mean = 0.f, rinv = 0.f;
      if (C.doln) { mean = mv[row][0]; rinv = mv[row][1]; }
      const size_t rowoff = (size_t)(m0 + row) * DD;
#pragma unroll
      for (int n = 0; n < 3; n++) {
        const int f = wf0 + n * 16 + llo;
        float v = acc[mf][n][r] + bia[n];
        if (C.doln) v = (v - mean) * rinv * gv[n] + bev[n];
        if (C.act == 1) v = fmaxf(v, 0.f);
        else if (C.act == 2) v = 0.5f * v * (1.f + erff(v * 0.7071067811865476f));
        if (AMODE == 0) C.hout[rowoff + f] = f2bf(v);
        else            C.fout[rowoff + f] = v;
      }
    }
  }
}

// ---------------------------------------------------------------- launch
extern "C" void kernel_launch(void* const* d_in, const int* in_sizes, int n_in,
                              void* d_out, int out_size, void* d_ws, size_t ws_size,
                              hipStream_t stream)
{
  (void)in_sizes; (void)n_in; (void)out_size;
  const float* comps  = (const float*)d_in[0];
  const float* geo    = (const float*)d_in[1];
  const float* qf     = (const float*)d_in[2];
  const int*   mask   = (const int*)d_in[3];
  const float* gp_w1  = (const float*)d_in[4];
  const float* gp_b1  = (const float*)d_in[5];
  const float* gp_g1  = (const float*)d_in[6];
  const float* gp_be1 = (const float*)d_in[7];
  const float* gp_w2  = (const float*)d_in[8];
  const float* gp_b2  = (const float*)d_in[9];
  const float* swp_w1 = (const float*)d_in[10];
  const float* swp_b1 = (const float*)d_in[11];
  const float* swp_g1 = (const float*)d_in[12];
  const float* swp_be1= (const float*)d_in[13];
  const float* swp_w2 = (const float*)d_in[14];
  const float* swp_b2 = (const float*)d_in[15];
  const float* swp_g2 = (const float*)d_in[16];
  const float* swp_be2= (const float*)d_in[17];
  const float* swp_w3 = (const float*)d_in[18];
  const float* swp_b3 = (const float*)d_in[19];
  const float* sw1 = (const float*)d_in[20];
  const float* sb1 = (const float*)d_in[21];
  const float* sg1 = (const float*)d_in[22];
  const float* sbe1= (const float*)d_in[23];
  const float* sw2 = (const float*)d_in[24];
  const float* sb2 = (const float*)d_in[25];
  const float* sg2 = (const float*)d_in[26];
  const float* sbe2= (const float*)d_in[27];
  const float* rw1 = (const float*)d_in[28];
  const float* rb1 = (const float*)d_in[29];
  const float* rg1 = (const float*)d_in[30];
  const float* rbe1= (const float*)d_in[31];
  const float* rw2 = (const float*)d_in[32];
  const float* rb2 = (const float*)d_in[33];
  float* out = (float*)d_out;

  char* ws = (char*)d_ws;
  float* gc_mean       = (float*)(ws + 0);
  unsigned short* cxs  = (unsigned short*)(ws + 53248);
  unsigned short* cxu  = (unsigned short*)(ws + 55296);
  unsigned short* s1t  = (unsigned short*)(ws + WS_WBASE);
  unsigned short* r1t  = (unsigned short*)(ws + 5177344);
  unsigned short* s2t  = (unsigned short*)(ws + 10289152);
  unsigned short* r2t  = (unsigned short*)(ws + 15007744);
  unsigned short* hb   = (unsigned short*)(ws + WS_HBASE);

  int NH;
  {
    size_t avail = (ws_size > (size_t)WS_HBASE) ? ws_size - WS_HBASE : 0;
    size_t n = avail / HB_SZ;
    NH = (int)(n < 1 ? 1 : (n > 8 ? 8 : n));
  }

  TArgs ta;
  ta.s[0] = sw1; ta.s[1] = sw2; ta.s[2] = rw1; ta.s[3] = rw2;
  ta.d[0] = s1t; ta.d[1] = s2t; ta.d[2] = r1t; ta.d[3] = r2t;
  ta.R[0] = 832; ta.R[1] = 768; ta.R[2] = 832; ta.R[3] = 768;
  transpose_cvt<<<dim3(24, 26, 16), 256, 0, stream>>>(ta);

  col_mean<<<dim3(6, 16), 128, 0, stream>>>(geo, gc_mean);
  small_mlp<<<16, 384, 0, stream>>>(gc_mean, qf, mask,
      gp_w1, gp_b1, gp_g1, gp_be1, gp_w2, gp_b2,
      swp_w1, swp_b1, swp_g1, swp_be1, swp_w2, swp_b2, swp_g2, swp_be2,
      swp_w3, swp_b3, cxs, cxu, out + AW_OFF);

  const int cis[8] = {0, 1, 3, 5, 4, 2, 6, 7};
  BrCfg cfg1[8], cfg2[8];
  for (int i = 0; i < 8; i++) {
    int ci = cis[i];
    BrCfg c1{}, c2{};
    c1.Afp = comps + (size_t)ci * MT * DD;
    c2.fout = out + (size_t)ci * MT * DD;
    if (i < 4) {
      c1.ctx = cxs;
      c1.wT = s1t + (size_t)i * DD * 832;
      c1.bias = sb1 + i * DD; c1.gam = sg1 + i * DD; c1.bet = sbe1 + i * DD;
      c1.act = 2; c1.doln = 1; c1.skip = 0;
      c2.wT = s2t + (size_t)i * DD * DD;
      c2.bias = sb2 + i * DD; c2.gam = sg2 + i * DD; c2.bet = sbe2 + i * DD;
      c2.act = 0; c2.doln = 1; c2.skip = 0;
    } else {
      int k = i - 4;
      c1.ctx = (k == 0) ? cxs : cxu;
      c1.wT = r1t + (size_t)k * DD * 832;
      c1.bias = rb1 + k * DD; c1.gam = rg1 + k * DD; c1.bet = rbe1 + k * DD;
      c1.act = 1; c1.doln = 1; c1.skip = (k == 0) ? 0 : 1;
      c2.wT = r2t + (size_t)k * DD * DD;
      c2.bias = rb2 + k * DD; c2.gam = nullptr; c2.bet = nullptr;
      c2.act = 0; c2.doln = 0; c2.skip = (k == 0) ? 0 : 1;
      c2.csel = comps + (size_t)ci * MT * DD;
    }
    cfg1[i] = c1; cfg2[i] = c2;
  }

  for (int g0 = 0; g0 < 8; ) {
    int gsz = (8 - g0 < NH) ? (8 - g0) : NH;
    PhaseArgs p1{}; p1.gsz = gsz;
    for (int j = 0; j < gsz; j++) {
      p1.c[j] = cfg1[g0 + j];
      p1.c[j].hout = hb + (size_t)j * MT * DD;
    }
    gemm_phase<0><<<gsz * 256, 1024, 0, stream>>>(p1, mask);
    PhaseArgs p2{}; p2.gsz = gsz;
    for (int j = 0; j < gsz; j++) {
      p2.c[j] = cfg2[g0 + j];
      p2.c[j].Abf = hb + (size_t)j * MT * DD;
    }
    gemm_phase<1><<<gsz * 256, 1024, 0, stream>>>(p2, mask);
    g0 += gsz;
  }
}

// Round 4
// 950.609 us; speedup vs baseline: 1.1206x; 1.0995x over previous
//
#include <hip/hip_runtime.h>
#include <math.h>

#define MT 16384          // B*N rows
#define DD 768
#define AW_OFF ((size_t)8 * MT * DD)

typedef __attribute__((ext_vector_type(8))) short short8;
typedef __attribute__((ext_vector_type(4))) float f32x4;
typedef __attribute__((ext_vector_type(4))) float fv4;
typedef __attribute__((ext_vector_type(4))) unsigned int u32x4;

// ---- workspace offsets (bytes) ----
#define OFF_W1T 0ULL                    // 8*768*832*2  = 10,223,616
#define OFF_W2T 10223616ULL             // 8*768*768*2  =  9,437,184
#define OFF_Z1  19660800ULL             // 8*MT*768*2   = 201,326,592
#define OFF_Z2  220987392ULL            // 4*MT*768*2   = 100,663,296
#define OFF_GB  321650688ULL            // 8*768*2*2    = 24,576
#define OFF_P1  321675264ULL            // 3*131072*8   = 3,145,728
#define OFF_P2  324820992ULL            // 3*65536*8    = 1,572,864
#define OFF_ST1 326393856ULL            // 131072*8     = 1,048,576
#define OFF_ST2 327442432ULL            // 65536*8      = 524,288
#define OFF_GP  327966720ULL            // 16*8*768*4   = 393,216
#define OFF_GM  328359936ULL            // 16*768*4     = 49,152
#define OFF_CXS 328409088ULL            // 2048
#define OFF_CXU 328411136ULL            // 2048

static __device__ __forceinline__ unsigned short f2bf(float f) {
  unsigned u = __float_as_uint(f);
  u += 0x7fffu + ((u >> 16) & 1u);
  return (unsigned short)(u >> 16);
}
static __device__ __forceinline__ float bf2f(unsigned short h) {
  return __uint_as_float(((unsigned)h) << 16);
}
static __device__ __forceinline__ unsigned pk2(float lo, float hi) {
  return (unsigned)f2bf(lo) | ((unsigned)f2bf(hi) << 16);
}
static __device__ __forceinline__ float gelu_t(float y) {
  // tanh-form gelu == y * sigmoid(y*(1.5957691 + 0.0713548*y^2)); max err ~3e-4
  float y2 = y * y;
  float c = fmaf(y2, 0.0713548163f, 1.59576912161f);
  float e = __expf(-y * c);
  return y / (1.0f + e);
}
static __device__ __forceinline__ void gload_lds16(const void* g, void* l) {
  __builtin_amdgcn_global_load_lds(
      (const __attribute__((address_space(1))) void*)g,
      (__attribute__((address_space(3))) void*)l, 16, 0, 0);
}

// ---------------------------------------------------------------- transpose
// 16 (K,768) fp32 weight mats -> (768,K) bf16.  z: 0-7 layer1 (K=832, s then r),
// 8-15 layer2 (K=768).
__global__ void transpose_cvt(const float* sw1, const float* rw1,
                              const float* sw2, const float* rw2,
                              unsigned short* w1T, unsigned short* w2T) {
  __shared__ float t[32][33];
  const int z = blockIdx.z;
  int R; const float* sp; unsigned short* dp;
  if (z < 8) {
    R = 832;
    sp = ((z < 4) ? sw1 : rw1) + (size_t)(z & 3) * 832 * DD;
    dp = w1T + (size_t)z * DD * 832;
  } else {
    R = 768;
    int zz = z - 8;
    sp = ((zz < 4) ? sw2 : rw2) + (size_t)(zz & 3) * DD * DD;
    dp = w2T + (size_t)zz * DD * DD;
  }
  const int r0 = blockIdx.x * 32, c0 = blockIdx.y * 32;
  if (r0 >= R) return;
  const int tx = threadIdx.x & 31, ty = threadIdx.x >> 5;
#pragma unroll
  for (int i = 0; i < 4; i++) {
    int r = ty + i * 8;
    t[r][tx] = sp[(size_t)(r0 + r) * DD + c0 + tx];
  }
  __syncthreads();
#pragma unroll
  for (int i = 0; i < 4; i++) {
    int cc = ty + i * 8;
    dp[(size_t)(c0 + cc) * R + r0 + tx] = f2bf(t[tx][cc]);
  }
}

// ---------------------------------------------------------------- gb pack
__global__ void pack_gb(const float* sg1, const float* sbe1,
                        const float* rg1, const float* rbe1,
                        unsigned short* gb1) {
  const int k = blockIdx.x * 256 + threadIdx.x;
  const int br = blockIdx.y;
  const float* gs = ((br < 4) ? sg1 : rg1) + (br & 3) * DD;
  const float* bs = ((br < 4) ? sbe1 : rbe1) + (br & 3) * DD;
  gb1[((size_t)br * DD + k) * 2]     = f2bf(gs[k]);
  gb1[((size_t)br * DD + k) * 2 + 1] = f2bf(bs[k]);
}

// ---------------------------------------------------------------- col mean
__global__ void colmean1(const float* __restrict__ geo, float* __restrict__ gp) {
  const int b = blockIdx.z, yc = blockIdx.y;
  const int col = blockIdx.x * 256 + threadIdx.x;
  const float* p = geo + (size_t)b * 1024 * DD + (size_t)yc * 128 * DD + col;
  float s = 0.f;
  for (int n = 0; n < 128; ++n) s += p[(size_t)n * DD];
  gp[((size_t)b * 8 + yc) * DD + col] = s;
}
__global__ void colmean2(const float* __restrict__ gp, float* __restrict__ gm) {
  const int b = blockIdx.y;
  const int col = blockIdx.x * 256 + threadIdx.x;
  float s = 0.f;
#pragma unroll
  for (int i = 0; i < 8; ++i) s += gp[((size_t)b * 8 + i) * DD + col];
  gm[(size_t)b * DD + col] = s * (1.0f / 1024.0f);
}

// ---------------------------------------------------------------- tiny MLPs
static __device__ float2 blk_sum2(float a, float b, float* red) {
  const int tid = threadIdx.x;   // blockDim == 384
  __syncthreads();
  red[tid] = a; red[512 + tid] = b;
  if (tid < 128) { red[384 + tid] = 0.f; red[512 + 384 + tid] = 0.f; }
  __syncthreads();
  for (int s = 256; s > 0; s >>= 1) {
    if (tid < s) { red[tid] += red[tid + s]; red[512 + tid] += red[512 + tid + s]; }
    __syncthreads();
  }
  return make_float2(red[0], red[512]);
}

__global__ void small_mlp(
    const float* __restrict__ gc_mean, const float* __restrict__ qf,
    const int* __restrict__ mask,
    const float* __restrict__ gp_w1, const float* __restrict__ gp_b1,
    const float* __restrict__ gp_g1, const float* __restrict__ gp_be1,
    const float* __restrict__ gp_w2, const float* __restrict__ gp_b2,
    const float* __restrict__ swp_w1, const float* __restrict__ swp_b1,
    const float* __restrict__ swp_g1, const float* __restrict__ swp_be1,
    const float* __restrict__ swp_w2, const float* __restrict__ swp_b2,
    const float* __restrict__ swp_g2, const float* __restrict__ swp_be2,
    const float* __restrict__ swp_w3, const float* __restrict__ swp_b3,
    unsigned short* __restrict__ ctxs, unsigned short* __restrict__ ctxu,
    float* __restrict__ aw)
{
  __shared__ float gm[768];
  __shared__ float buf[832];
  __shared__ float tmp[384];
  __shared__ float red[1024];
  const int b = blockIdx.x, tid = threadIdx.x;

  for (int i = tid; i < 768; i += 384) gm[i] = gc_mean[b * 768 + i];
  __syncthreads();

  float z = gp_b1[tid];
  for (int k = 0; k < 768; k++) z += gm[k] * gp_w1[k * 384 + tid];
  float2 s = blk_sum2(z, z * z, red);
  {
    float mean = s.x * (1.f / 384.f);
    float rinv = rsqrtf(s.y * (1.f / 384.f) - mean * mean + 1e-5f);
    float y = (z - mean) * rinv * gp_g1[tid] + gp_be1[tid];
    tmp[tid] = fmaxf(y, 0.f);
  }
  __syncthreads();

  if (tid < 64) {
    float g = gp_b2[tid];
    for (int k = 0; k < 384; k++) g += tmp[k] * gp_w2[k * 64 + tid];
    float sc = (mask[b] != 0) ? 1.0f : 0.1f;
    ctxs[b * 64 + tid] = f2bf(g * sc);
    ctxu[b * 64 + tid] = f2bf(g);
    buf[tid] = g;
  }
  for (int i = tid; i < 768; i += 384) buf[64 + i] = qf[b * 768 + i];
  __syncthreads();

  float z1 = 0.f;
  if (tid < 256) {
    z1 = swp_b1[tid];
    for (int k = 0; k < 832; k++) z1 += buf[k] * swp_w1[k * 256 + tid];
  }
  s = blk_sum2(z1, z1 * z1, red);
  {
    float mean = s.x * (1.f / 256.f);
    float rinv = rsqrtf(s.y * (1.f / 256.f) - mean * mean + 1e-5f);
    if (tid < 256) {
      float y = (z1 - mean) * rinv * swp_g1[tid] + swp_be1[tid];
      tmp[tid] = 0.5f * y * (1.f + erff(y * 0.7071067811865476f));
    }
  }
  __syncthreads();

  float z2 = 0.f;
  if (tid < 128) {
    z2 = swp_b2[tid];
    for (int k = 0; k < 256; k++) z2 += tmp[k] * swp_w2[k * 128 + tid];
  }
  s = blk_sum2(z2, z2 * z2, red);
  {
    float mean = s.x * (1.f / 128.f);
    float rinv = rsqrtf(s.y * (1.f / 128.f) - mean * mean + 1e-5f);
    if (tid < 128) {
      float y = (z2 - mean) * rinv * swp_g2[tid] + swp_be2[tid];
      tmp[tid] = 0.5f * y * (1.f + erff(y * 0.7071067811865476f));
    }
  }
  __syncthreads();

  if (tid < 8) {
    float z3 = swp_b3[tid];
    for (int k = 0; k < 128; k++) z3 += tmp[k] * swp_w3[k * 8 + tid];
    buf[tid] = z3;
  }
  __syncthreads();
  if (tid < 8) {
    float mx = buf[0];
    for (int k = 1; k < 8; k++) mx = fmaxf(mx, buf[k]);
    float ssum = 0.f;
    for (int k = 0; k < 8; k++) ssum += expf(buf[k] - mx);
    aw[b * 8 + tid] = expf(buf[tid] - mx) / ssum;
  }
}

// ---------------------------------------------------------------- stats
__global__ void stats_k(const float2* __restrict__ part, float2* __restrict__ st,
                        int nr) {
  int i = blockIdx.x * 256 + threadIdx.x;
  if (i >= nr) return;
  float2 p0 = part[i], p1 = part[nr + i], p2 = part[2 * nr + i];
  float s1 = p0.x + p1.x + p2.x, s2 = p0.y + p1.y + p2.y;
  float mean = s1 * (1.f / 768.f);
  float var = s2 * (1.f / 768.f) - mean * mean;
  float rinv = rsqrtf(var + 1e-5f);
  st[i] = make_float2(rinv, -mean * rinv);
}

// ================================================================ GEMM1
// 256x256x(K=832) bf16 MFMA, 8 waves, 3-slot LDS ring, depth-2 prefetch,
// one raw barrier / K-step. A = comps fp32 (+ctx bf16 cols 768..831) staged
// manually; B = w1T via global_load_lds (inverse-swizzled source).
// Out: z1 bf16 + per-row (sum, sumsq) partials (per-nt slot, no atomics).
__global__ __launch_bounds__(512, 2)
void gemm1_k(const float* __restrict__ comps,
             const unsigned short* __restrict__ cxs,
             const unsigned short* __restrict__ cxu,
             const unsigned short* __restrict__ w1T,
             const float* __restrict__ sb1, const float* __restrict__ rb1,
             unsigned short* __restrict__ z1,
             float2* __restrict__ part1,
             const int* __restrict__ mask)
{
  __shared__ __align__(16) unsigned short As[3][8192];
  __shared__ __align__(16) unsigned short Bs[3][8192];
  __shared__ float pscr[4][256][2];
  constexpr int NT = 26;

  const int id = blockIdx.x;
  // XCD-aware: x = id&7 (XCD), per-XCD stream j = id>>3; 8 consecutive j share (br,nt)
  const int x = id & 7, j = id >> 3;
  const int br_nt = j >> 3;                 // 0..23
  const int mt = ((j & 7) << 3) | x;        // 0..63
  const int nt = br_nt % 3;
  const int br = br_nt / 3;                 // 0..7
  const int m0 = mt * 256, n0 = nt * 256;
  const int b = m0 >> 10;
  const int msk = mask[b];
  if (br >= 5 && msk == 0) return;          // masked r-branch: h unused

  const int ci = (0x76245310u >> (br * 4)) & 15;
  const float* afp = comps + (size_t)ci * MT * DD + (size_t)m0 * DD;
  const unsigned short* ctxp = ((br <= 4) ? cxs : cxu) + b * 64;
  const unsigned short* wT = w1T + (size_t)br * DD * 832 + (size_t)n0 * 832;
  const float* bias = ((br < 4) ? sb1 : rb1) + (br & 3) * DD;
  unsigned short* zo = z1 + (size_t)br * MT * DD + (size_t)m0 * DD;

  const int tid = threadIdx.x;
  const int w = tid >> 6, lane = tid & 63, llo = lane & 15, lhi = lane >> 4;
  const int wm = w & 1, wn = w >> 1;
  const int q = tid & 3, rr = tid >> 2;                 // rr 0..127
  const int swq = q ^ ((tid >> 3) & 3);                 // swizzled slot/source chunk

  const unsigned short* bsrc0 = wT + (size_t)rr * 832 + swq * 8;
  const unsigned short* bsrc1 = wT + (size_t)(128 + rr) * 832 + swq * 8;
  const float* asrc0 = afp + (size_t)rr * DD + q * 8;
  const float* asrc1 = afp + (size_t)(128 + rr) * DD + q * 8;
  const unsigned short* csrc = ctxp + q * 8;

  f32x4 acc[8][4];
#pragma unroll
  for (int mf = 0; mf < 8; ++mf)
#pragma unroll
    for (int nf = 0; nf < 4; ++nf) acc[mf][nf] = (f32x4)0.0f;

  struct St { fv4 f0, f1, f2, f3; u32x4 c; };

  auto issueB = [&](int kt, int s) {
    gload_lds16(bsrc0 + (size_t)kt * 32, &Bs[s][w * 512]);
    gload_lds16(bsrc1 + (size_t)kt * 32, &Bs[s][4096 + w * 512]);
  };
  auto issueA = [&](int kt) -> St {
    St s;
    if (kt < 24) {
      const float* p0 = asrc0 + kt * 32;
      s.f0 = *(const fv4*)p0; s.f1 = *(const fv4*)(p0 + 4);
      const float* p1 = asrc1 + kt * 32;
      s.f2 = *(const fv4*)p1; s.f3 = *(const fv4*)(p1 + 4);
    } else {
      s.c = *(const u32x4*)(csrc + (kt - 24) * 32);
    }
    return s;
  };
  auto commitA = [&](const St& s, int kt, int sl) {
    u32x4* d0 = (u32x4*)&As[sl][rr * 32 + swq * 8];
    u32x4* d1 = (u32x4*)&As[sl][(128 + rr) * 32 + swq * 8];
    if (kt < 24) {
      u32x4 v0, v1;
      v0[0] = pk2(s.f0[0], s.f0[1]); v0[1] = pk2(s.f0[2], s.f0[3]);
      v0[2] = pk2(s.f1[0], s.f1[1]); v0[3] = pk2(s.f1[2], s.f1[3]);
      v1[0] = pk2(s.f2[0], s.f2[1]); v1[1] = pk2(s.f2[2], s.f2[3]);
      v1[2] = pk2(s.f3[0], s.f3[1]); v1[3] = pk2(s.f3[2], s.f3[3]);
      *d0 = v0; *d1 = v1;
    } else {
      *d0 = s.c; *d1 = s.c;                // ctx broadcast over rows
    }
  };
  const int aswz = (lhi ^ ((llo >> 1) & 3)) << 3;
  const int arow0 = (wm * 128 + llo) * 32 + aswz;
  const int brow0 = (wn * 64 + llo) * 32 + aswz;
  auto compute = [&](int sl) {
    const unsigned short* Ab = &As[sl][0];
    const unsigned short* Bb = &Bs[sl][0];
    short8 bfr[4];
#pragma unroll
    for (int nf = 0; nf < 4; ++nf) bfr[nf] = *(const short8*)&Bb[brow0 + nf * 512];
#pragma unroll
    for (int mf = 0; mf < 8; ++mf) {
      short8 a = *(const short8*)&Ab[arow0 + mf * 512];
#pragma unroll
      for (int nf = 0; nf < 4; ++nf)
        acc[mf][nf] = __builtin_amdgcn_mfma_f32_16x16x32_bf16(a, bfr[nf], acc[mf][nf], 0, 0, 0);
    }
  };

  // prologue: tiles 0,1 in flight; tile 0 committed
  issueB(0, 0);
  __builtin_amdgcn_sched_barrier(0);
  St s0 = issueA(0);
  __builtin_amdgcn_sched_barrier(0);
  issueB(1, 1);
  __builtin_amdgcn_sched_barrier(0);
  St s1 = issueA(1);
  __builtin_amdgcn_sched_barrier(0);
  commitA(s0, 0, 0);                       // auto-vmcnt => B(0) DMA retired
  asm volatile("s_waitcnt lgkmcnt(0)" ::: "memory");
  __builtin_amdgcn_sched_barrier(0);
  __builtin_amdgcn_s_barrier();

  St sCur = s1;
  int sl = 0;
#pragma unroll 1
  for (int t = 0; t < NT; ++t) {
    int sl1 = sl + 1; if (sl1 == 3) sl1 = 0;
    int sl2 = sl1 + 1; if (sl2 == 3) sl2 = 0;
    St sNxt = sCur;
    if (t + 2 < NT) {
      issueB(t + 2, sl2);
      __builtin_amdgcn_sched_barrier(0);   // pin: B issue precedes A issue
      sNxt = issueA(t + 2);
      __builtin_amdgcn_sched_barrier(0);
    }
    if (t + 1 < NT) commitA(sCur, t + 1, sl1);  // auto-vmcnt => B(t+1) retired
    compute(sl);
    asm volatile("s_waitcnt lgkmcnt(0)" ::: "memory");
    __builtin_amdgcn_sched_barrier(0);
    __builtin_amdgcn_s_barrier();
    sCur = sNxt; sl = sl1;
  }

  // epilogue: bias, z-store (bf16, lane-paired), row partials
  const int n0w = n0 + wn * 64;
  float bia[4];
#pragma unroll
  for (int nf = 0; nf < 4; ++nf) bia[nf] = bias[n0w + nf * 16 + llo];
#pragma unroll
  for (int mf = 0; mf < 8; ++mf) {
#pragma unroll
    for (int r = 0; r < 4; ++r) {
      float zz[4]; float s1v = 0.f, s2v = 0.f;
#pragma unroll
      for (int nf = 0; nf < 4; ++nf) {
        float zv = acc[mf][nf][r] + bia[nf];
        zz[nf] = zv; s1v += zv; s2v += zv * zv;
      }
      const int rloc = wm * 128 + mf * 16 + lhi * 4 + r;
      const size_t rowoff = (size_t)rloc * DD;
#pragma unroll
      for (int nf = 0; nf < 4; ++nf) {
        float zon = __shfl_xor(zz[nf], 1);
        if ((llo & 1) == 0)
          *(unsigned*)&zo[rowoff + n0w + nf * 16 + llo] = pk2(zz[nf], zon);
      }
#pragma unroll
      for (int d = 1; d < 16; d <<= 1) {
        s1v += __shfl_xor(s1v, d); s2v += __shfl_xor(s2v, d);
      }
      if (llo == 0) { pscr[wn][rloc][0] = s1v; pscr[wn][rloc][1] = s2v; }
    }
  }
  __syncthreads();
  if (tid < 256) {
    float a = 0.f, c = 0.f;
#pragma unroll
    for (int qq = 0; qq < 4; ++qq) { a += pscr[qq][tid][0]; c += pscr[qq][tid][1]; }
    part1[(size_t)nt * (8 * MT) + (size_t)br * MT + m0 + tid] = make_float2(a, c);
  }
}

// ================================================================ GEMM2
// SBR=1: s-branches (A = gelu(ln(z1)), out z2-bf16 + partials)
// SBR=0: r-branches (A = relu(ln(z1)), out fp32 direct; masked k>=1 -> copy)
template<int SBR>
__global__ __launch_bounds__(512, 2)
void gemm2_k(const float* __restrict__ comps,
             const unsigned short* __restrict__ z1,
             const float2* __restrict__ st1,
             const unsigned short* __restrict__ gb1,
             const unsigned short* __restrict__ w2T,
             const float* __restrict__ sb2, const float* __restrict__ rb2,
             unsigned short* __restrict__ z2,
             float2* __restrict__ part2,
             float* __restrict__ outp,
             const int* __restrict__ mask)
{
  __shared__ __align__(16) unsigned short As[3][8192];
  __shared__ __align__(16) unsigned short Bs[3][8192];
  __shared__ float pscr[4][256][2];
  constexpr int NT = 24;

  const int id = blockIdx.x;
  const int x = id & 7, j = id >> 3;
  const int br_nt = j >> 3;                 // 0..11
  const int mt = ((j & 7) << 3) | x;
  const int nt = br_nt % 3;
  const int brl = br_nt / 3;                // 0..3
  const int br = SBR ? brl : (brl + 4);
  const int m0 = mt * 256, n0 = nt * 256;
  const int b = m0 >> 10;
  const int msk = mask[b];
  const int ci = (0x76245310u >> (br * 4)) & 15;
  const int tid = threadIdx.x;

  if (!SBR && br >= 5 && msk == 0) {        // masked: out = comps
    const float* cs = comps + (size_t)ci * MT * DD + (size_t)m0 * DD + n0;
    float* cd = outp + (size_t)ci * MT * DD + (size_t)m0 * DD + n0;
#pragma unroll 1
    for (int k = 0; k < 32; ++k) {
      int idx = tid + k * 512;
      int r2 = idx >> 6, c4 = (idx & 63) * 4;
      *(fv4*)(cd + (size_t)r2 * DD + c4) = *(const fv4*)(cs + (size_t)r2 * DD + c4);
    }
    return;
  }

  const unsigned short* az = z1 + (size_t)br * MT * DD + (size_t)m0 * DD;
  const unsigned short* wT = w2T + (size_t)br * DD * DD + (size_t)n0 * DD;
  const float* bias = (SBR ? sb2 : rb2) + (br & 3) * DD;

  const int w = tid >> 6, lane = tid & 63, llo = lane & 15, lhi = lane >> 4;
  const int wm = w & 1, wn = w >> 1;
  const int q = tid & 3, rr = tid >> 2;
  const int swq = q ^ ((tid >> 3) & 3);

  const unsigned short* bsrc0 = wT + (size_t)rr * DD + swq * 8;
  const unsigned short* bsrc1 = wT + (size_t)(128 + rr) * DD + swq * 8;
  const unsigned short* zsrc0 = az + (size_t)rr * DD + q * 8;
  const unsigned short* zsrc1 = az + (size_t)(128 + rr) * DD + q * 8;
  const unsigned short* gsrc = gb1 + (size_t)br * DD * 2 + q * 16;
  const float2 stv0 = st1[(size_t)br * MT + m0 + rr];
  const float2 stv1 = st1[(size_t)br * MT + m0 + 128 + rr];

  f32x4 acc[8][4];
#pragma unroll
  for (int mf = 0; mf < 8; ++mf)
#pragma unroll
    for (int nf = 0; nf < 4; ++nf) acc[mf][nf] = (f32x4)0.0f;

  struct St { u32x4 z0, z1v, g0, g1; };

  auto issueB = [&](int kt, int s) {
    gload_lds16(bsrc0 + (size_t)kt * 32, &Bs[s][w * 512]);
    gload_lds16(bsrc1 + (size_t)kt * 32, &Bs[s][4096 + w * 512]);
  };
  auto issueA = [&](int kt) -> St {
    St s;
    s.z0  = *(const u32x4*)(zsrc0 + kt * 32);
    s.z1v = *(const u32x4*)(zsrc1 + kt * 32);
    s.g0  = *(const u32x4*)(gsrc + kt * 64);
    s.g1  = *(const u32x4*)(gsrc + kt * 64 + 8);
    return s;
  };
  // z word wd holds elements 2wd,2wd+1 whose (g,be) coeffs are words 2wd, 2wd+1.
  auto xform2 = [&](unsigned zw, unsigned gwa, unsigned gwb, float2 stv) -> unsigned {
    float z0 = bf2f((unsigned short)(zw & 0xffffu));
    float z1f = bf2f((unsigned short)(zw >> 16));
    float g0 = bf2f((unsigned short)(gwa & 0xffffu));
    float be0 = bf2f((unsigned short)(gwa >> 16));
    float g1 = bf2f((unsigned short)(gwb & 0xffffu));
    float be1 = bf2f((unsigned short)(gwb >> 16));
    float y0 = fmaf(fmaf(z0, stv.x, stv.y), g0, be0);
    float y1 = fmaf(fmaf(z1f, stv.x, stv.y), g1, be1);
    if (SBR) { y0 = gelu_t(y0); y1 = gelu_t(y1); }
    else     { y0 = fmaxf(y0, 0.f); y1 = fmaxf(y1, 0.f); }
    return pk2(y0, y1);
  };
  auto commitA2 = [&](const St& s, int sl) {
    u32x4 v0, v1;
    v0[0] = xform2(s.z0[0], s.g0[0], s.g0[1], stv0);
    v0[1] = xform2(s.z0[1], s.g0[2], s.g0[3], stv0);
    v0[2] = xform2(s.z0[2], s.g1[0], s.g1[1], stv0);
    v0[3] = xform2(s.z0[3], s.g1[2], s.g1[3], stv0);
    v1[0] = xform2(s.z1v[0], s.g0[0], s.g0[1], stv1);
    v1[1] = xform2(s.z1v[1], s.g0[2], s.g0[3], stv1);
    v1[2] = xform2(s.z1v[2], s.g1[0], s.g1[1], stv1);
    v1[3] = xform2(s.z1v[3], s.g1[2], s.g1[3], stv1);
    *(u32x4*)&As[sl][rr * 32 + swq * 8] = v0;
    *(u32x4*)&As[sl][(128 + rr) * 32 + swq * 8] = v1;
  };

  const int aswz = (lhi ^ ((llo >> 1) & 3)) << 3;
  const int arow0 = (wm * 128 + llo) * 32 + aswz;
  const int brow0 = (wn * 64 + llo) * 32 + aswz;
  auto compute = [&](int sl) {
    const unsigned short* Ab = &As[sl][0];
    const unsigned short* Bb = &Bs[sl][0];
    short8 bfr[4];
#pragma unroll
    for (int nf = 0; nf < 4; ++nf) bfr[nf] = *(const short8*)&Bb[brow0 + nf * 512];
#pragma unroll
    for (int mf = 0; mf < 8; ++mf) {
      short8 a = *(const short8*)&Ab[arow0 + mf * 512];
#pragma unroll
      for (int nf = 0; nf < 4; ++nf)
        acc[mf][nf] = __builtin_amdgcn_mfma_f32_16x16x32_bf16(a, bfr[nf], acc[mf][nf], 0, 0, 0);
    }
  };

  issueB(0, 0);
  __builtin_amdgcn_sched_barrier(0);
  St s0 = issueA(0);
  __builtin_amdgcn_sched_barrier(0);
  issueB(1, 1);
  __builtin_amdgcn_sched_barrier(0);
  St s1 = issueA(1);
  __builtin_amdgcn_sched_barrier(0);
  commitA2(s0, 0);
  asm volatile("s_waitcnt lgkmcnt(0)" ::: "memory");
  __builtin_amdgcn_sched_barrier(0);
  __builtin_amdgcn_s_barrier();

  St sCur = s1;
  int sl = 0;
#pragma unroll 1
  for (int t = 0; t < NT; ++t) {
    int sl1 = sl + 1; if (sl1 == 3) sl1 = 0;
    int sl2 = sl1 + 1; if (sl2 == 3) sl2 = 0;
    St sNxt = sCur;
    if (t + 2 < NT) {
      issueB(t + 2, sl2);
      __builtin_amdgcn_sched_barrier(0);
      sNxt = issueA(t + 2);
      __builtin_amdgcn_sched_barrier(0);
    }
    if (t + 1 < NT) commitA2(sCur, sl1);
    compute(sl);
    asm volatile("s_waitcnt lgkmcnt(0)" ::: "memory");
    __builtin_amdgcn_sched_barrier(0);
    __builtin_amdgcn_s_barrier();
    sCur = sNxt; sl = sl1;
  }

  const int n0w = n0 + wn * 64;
  float bia[4];
#pragma unroll
  for (int nf = 0; nf < 4; ++nf) bia[nf] = bias[n0w + nf * 16 + llo];

  if (SBR) {
    unsigned short* zo = z2 + (size_t)br * MT * DD + (size_t)m0 * DD;
#pragma unroll
    for (int mf = 0; mf < 8; ++mf) {
#pragma unroll
      for (int r = 0; r < 4; ++r) {
        float zz[4]; float s1v = 0.f, s2v = 0.f;
#pragma unroll
        for (int nf = 0; nf < 4; ++nf) {
          float zv = acc[mf][nf][r] + bia[nf];
          zz[nf] = zv; s1v += zv; s2v += zv * zv;
        }
        const int rloc = wm * 128 + mf * 16 + lhi * 4 + r;
        const size_t rowoff = (size_t)rloc * DD;
#pragma unroll
        for (int nf = 0; nf < 4; ++nf) {
          float zon = __shfl_xor(zz[nf], 1);
          if ((llo & 1) == 0)
            *(unsigned*)&zo[rowoff + n0w + nf * 16 + llo] = pk2(zz[nf], zon);
        }
#pragma unroll
        for (int d = 1; d < 16; d <<= 1) {
          s1v += __shfl_xor(s1v, d); s2v += __shfl_xor(s2v, d);
        }
        if (llo == 0) { pscr[wn][rloc][0] = s1v; pscr[wn][rloc][1] = s2v; }
      }
    }
    __syncthreads();
    if (tid < 256) {
      float a = 0.f, c = 0.f;
#pragma unroll
      for (int qq = 0; qq < 4; ++qq) { a += pscr[qq][tid][0]; c += pscr[qq][tid][1]; }
      part2[(size_t)nt * (4 * MT) + (size_t)br * MT + m0 + tid] = make_float2(a, c);
    }
  } else {
    float* fo = outp + (size_t)ci * MT * DD + (size_t)m0 * DD;
#pragma unroll
    for (int mf = 0; mf < 8; ++mf) {
#pragma unroll
      for (int r = 0; r < 4; ++r) {
        const int rloc = wm * 128 + mf * 16 + lhi * 4 + r;
        const size_t rowoff = (size_t)rloc * DD;
#pragma unroll
        for (int nf = 0; nf < 4; ++nf)
          fo[rowoff + n0w + nf * 16 + llo] = acc[mf][nf][r] + bia[nf];
      }
    }
  }
}

// ---------------------------------------------------------------- finish s
__global__ void finish_s(const unsigned short* __restrict__ z2,
                         const float2* __restrict__ st2,
                         const float* __restrict__ sg2,
                         const float* __restrict__ sbe2,
                         float* __restrict__ outp)
{
  const int tid = threadIdx.x;
  const int rowg = blockIdx.x * 8 + (tid >> 5);     // 0..65535
  const int l = tid & 31;
  const int br = rowg >> 14;
  const int r = rowg & 16383;
  const int ci = (0x5310u >> (br * 4)) & 15;
  const unsigned short* zp = z2 + (size_t)rowg * DD;
  float* op = outp + (size_t)ci * MT * DD + (size_t)r * DD;
  const float2 stv = st2[rowg];
  const float* g = sg2 + br * DD;
  const float* be = sbe2 + br * DD;
#pragma unroll
  for (int c = 0; c < 3; ++c) {
    const int col = l * 8 + c * 256;
    u32x4 zv = *(const u32x4*)(zp + col);
    fv4 ga = *(const fv4*)(g + col), gb = *(const fv4*)(g + col + 4);
    fv4 ba = *(const fv4*)(be + col), bb = *(const fv4*)(be + col + 4);
    fv4 o0, o1;
#pragma unroll
    for (int wd = 0; wd < 2; ++wd) {
      o0[2 * wd]     = fmaf(fmaf(bf2f((unsigned short)(zv[wd] & 0xffffu)), stv.x, stv.y), ga[2 * wd], ba[2 * wd]);
      o0[2 * wd + 1] = fmaf(fmaf(bf2f((unsigned short)(zv[wd] >> 16)), stv.x, stv.y), ga[2 * wd + 1], ba[2 * wd + 1]);
      o1[2 * wd]     = fmaf(fmaf(bf2f((unsigned short)(zv[wd + 2] & 0xffffu)), stv.x, stv.y), gb[2 * wd], bb[2 * wd]);
      o1[2 * wd + 1] = fmaf(fmaf(bf2f((unsigned short)(zv[wd + 2] >> 16)), stv.x, stv.y), gb[2 * wd + 1], bb[2 * wd + 1]);
    }
    *(fv4*)(op + col) = o0;
    *(fv4*)(op + col + 4) = o1;
  }
}

// ---------------------------------------------------------------- launch
extern "C" void kernel_launch(void* const* d_in, const int* in_sizes, int n_in,
                              void* d_out, int out_size, void* d_ws, size_t ws_size,
                              hipStream_t stream)
{
  (void)in_sizes; (void)n_in; (void)out_size; (void)ws_size;
  const float* comps  = (const float*)d_in[0];
  const float* geo    = (const float*)d_in[1];
  const float* qf     = (const float*)d_in[2];
  const int*   mask   = (const int*)d_in[3];
  const float* gp_w1  = (const float*)d_in[4];
  const float* gp_b1  = (const float*)d_in[5];
  const float* gp_g1  = (const float*)d_in[6];
  const float* gp_be1 = (const float*)d_in[7];
  const float* gp_w2  = (const float*)d_in[8];
  const float* gp_b2  = (const float*)d_in[9];
  const float* swp_w1 = (const float*)d_in[10];
  const float* swp_b1 = (const float*)d_in[11];
  const float* swp_g1 = (const float*)d_in[12];
  const float* swp_be1= (const float*)d_in[13];
  const float* swp_w2 = (const float*)d_in[14];
  const float* swp_b2 = (const float*)d_in[15];
  const float* swp_g2 = (const float*)d_in[16];
  const float* swp_be2= (const float*)d_in[17];
  const float* swp_w3 = (const float*)d_in[18];
  const float* swp_b3 = (const float*)d_in[19];
  const float* sw1 = (const float*)d_in[20];
  const float* sb1 = (const float*)d_in[21];
  const float* sg1 = (const float*)d_in[22];
  const float* sbe1= (const float*)d_in[23];
  const float* sw2 = (const float*)d_in[24];
  const float* sb2 = (const float*)d_in[25];
  const float* sg2 = (const float*)d_in[26];
  const float* sbe2= (const float*)d_in[27];
  const float* rw1 = (const float*)d_in[28];
  const float* rb1 = (const float*)d_in[29];
  const float* rg1 = (const float*)d_in[30];
  const float* rbe1= (const float*)d_in[31];
  const float* rw2 = (const float*)d_in[32];
  const float* rb2 = (const float*)d_in[33];
  float* out = (float*)d_out;

  char* ws = (char*)d_ws;
  unsigned short* w1T = (unsigned short*)(ws + OFF_W1T);
  unsigned short* w2T = (unsigned short*)(ws + OFF_W2T);
  unsigned short* z1  = (unsigned short*)(ws + OFF_Z1);
  unsigned short* z2  = (unsigned short*)(ws + OFF_Z2);
  unsigned short* gb1 = (unsigned short*)(ws + OFF_GB);
  float2* part1 = (float2*)(ws + OFF_P1);
  float2* part2 = (float2*)(ws + OFF_P2);
  float2* st1   = (float2*)(ws + OFF_ST1);
  float2* st2   = (float2*)(ws + OFF_ST2);
  float* gpart  = (float*)(ws + OFF_GP);
  float* gmean  = (float*)(ws + OFF_GM);
  unsigned short* cxs = (unsigned short*)(ws + OFF_CXS);
  unsigned short* cxu = (unsigned short*)(ws + OFF_CXU);

  transpose_cvt<<<dim3(26, 24, 16), 256, 0, stream>>>(sw1, rw1, sw2, rw2, w1T, w2T);
  pack_gb<<<dim3(3, 8), 256, 0, stream>>>(sg1, sbe1, rg1, rbe1, gb1);
  colmean1<<<dim3(3, 8, 16), 256, 0, stream>>>(geo, gpart);
  colmean2<<<dim3(3, 16), 256, 0, stream>>>(gpart, gmean);
  small_mlp<<<16, 384, 0, stream>>>(gmean, qf, mask,
      gp_w1, gp_b1, gp_g1, gp_be1, gp_w2, gp_b2,
      swp_w1, swp_b1, swp_g1, swp_be1, swp_w2, swp_b2, swp_g2, swp_be2,
      swp_w3, swp_b3, cxs, cxu, out + AW_OFF);

  hipMemsetAsync(part1, 0, 3 * 8 * MT * sizeof(float2), stream);
  hipMemsetAsync(part2, 0, 3 * 4 * MT * sizeof(float2), stream);

  gemm1_k<<<1536, 512, 0, stream>>>(comps, cxs, cxu, w1T, sb1, rb1, z1, part1, mask);
  stats_k<<<512, 256, 0, stream>>>(part1, st1, 8 * MT);
  gemm2_k<1><<<768, 512, 0, stream>>>(comps, z1, st1, gb1, w2T, sb2, rb2,
                                      z2, part2, out, mask);
  gemm2_k<0><<<768, 512, 0, stream>>>(comps, z1, st1, gb1, w2T, sb2, rb2,
                                      z2, part2, out, mask);
  stats_k<<<256, 256, 0, stream>>>(part2, st2, 4 * MT);
  finish_s<<<8192, 256, 0, stream>>>(z2, st2, sg2, sbe2, out);
}

// Round 5
// 774.669 us; speedup vs baseline: 1.3751x; 1.2271x over previous
//
#include <hip/hip_runtime.h>
#include <math.h>

#define MT 16384          // B*N rows
#define DD 768
#define AW_OFF ((size_t)8 * MT * DD)

typedef __attribute__((ext_vector_type(8))) short short8;
typedef __attribute__((ext_vector_type(4))) float f32x4;
typedef __attribute__((ext_vector_type(4))) float fv4;
typedef __attribute__((ext_vector_type(4))) unsigned int u32x4;

// ---- workspace offsets (bytes) ----
#define OFF_W1T 0ULL                    // 8*768*832*2  = 10,223,616
#define OFF_W2T 10223616ULL             // 8*768*768*2  =  9,437,184
#define OFF_Z1  19660800ULL             // 8*MT*768*2   = 201,326,592
#define OFF_Z2  220987392ULL            // 4*MT*768*2   = 100,663,296
#define OFF_P1  321675264ULL            // 3*131072*8   = 3,145,728
#define OFF_P2  324820992ULL            // 3*65536*8    = 1,572,864
#define OFF_ST1 326393856ULL            // 131072*8     = 1,048,576
#define OFF_ST2 327442432ULL            // 65536*8      = 524,288
#define OFF_GP  327966720ULL            // 16*8*768*4   = 393,216
#define OFF_GM  328359936ULL            // 16*768*4     = 49,152
#define OFF_CXS 328409088ULL            // 2048
#define OFF_CXU 328411136ULL            // 2048
#define OFF_A1  335544320ULL            // 8*MT*768*2   = 201,326,592

static __device__ __forceinline__ unsigned short f2bf(float f) {
  unsigned u = __float_as_uint(f);
  u += 0x7fffu + ((u >> 16) & 1u);
  return (unsigned short)(u >> 16);
}
static __device__ __forceinline__ float bf2f(unsigned short h) {
  return __uint_as_float(((unsigned)h) << 16);
}
static __device__ __forceinline__ unsigned pk2(float lo, float hi) {
  return (unsigned)f2bf(lo) | ((unsigned)f2bf(hi) << 16);
}
static __device__ __forceinline__ float gelu_t(float y) {
  float y2 = y * y;
  float c = fmaf(y2, 0.0713548163f, 1.59576912161f);
  float e = __expf(-y * c);
  return y / (1.0f + e);
}
static __device__ __forceinline__ void gload_lds16(const void* g, void* l) {
  __builtin_amdgcn_global_load_lds(
      (const __attribute__((address_space(1))) void*)g,
      (__attribute__((address_space(3))) void*)l, 16, 0, 0);
}

// ---------------------------------------------------------------- transpose
__global__ void transpose_cvt(const float* sw1, const float* rw1,
                              const float* sw2, const float* rw2,
                              unsigned short* w1T, unsigned short* w2T) {
  __shared__ float t[32][33];
  const int z = blockIdx.z;
  int R; const float* sp; unsigned short* dp;
  if (z < 8) {
    R = 832;
    sp = ((z < 4) ? sw1 : rw1) + (size_t)(z & 3) * 832 * DD;
    dp = w1T + (size_t)z * DD * 832;
  } else {
    R = 768;
    int zz = z - 8;
    sp = ((zz < 4) ? sw2 : rw2) + (size_t)(zz & 3) * DD * DD;
    dp = w2T + (size_t)zz * DD * DD;
  }
  const int r0 = blockIdx.x * 32, c0 = blockIdx.y * 32;
  if (r0 >= R) return;
  const int tx = threadIdx.x & 31, ty = threadIdx.x >> 5;
#pragma unroll
  for (int i = 0; i < 4; i++) {
    int r = ty + i * 8;
    t[r][tx] = sp[(size_t)(r0 + r) * DD + c0 + tx];
  }
  __syncthreads();
#pragma unroll
  for (int i = 0; i < 4; i++) {
    int cc = ty + i * 8;
    dp[(size_t)(c0 + cc) * R + r0 + tx] = f2bf(t[tx][cc]);
  }
}

// ---------------------------------------------------------------- col mean
__global__ void colmean1(const float* __restrict__ geo, float* __restrict__ gp) {
  const int b = blockIdx.z, yc = blockIdx.y;
  const int col = blockIdx.x * 256 + threadIdx.x;
  const float* p = geo + (size_t)b * 1024 * DD + (size_t)yc * 128 * DD + col;
  float s = 0.f;
  for (int n = 0; n < 128; ++n) s += p[(size_t)n * DD];
  gp[((size_t)b * 8 + yc) * DD + col] = s;
}
__global__ void colmean2(const float* __restrict__ gp, float* __restrict__ gm) {
  const int b = blockIdx.y;
  const int col = blockIdx.x * 256 + threadIdx.x;
  float s = 0.f;
#pragma unroll
  for (int i = 0; i < 8; ++i) s += gp[((size_t)b * 8 + i) * DD + col];
  gm[(size_t)b * DD + col] = s * (1.0f / 1024.0f);
}

// ---------------------------------------------------------------- tiny MLPs
static __device__ float2 blk_sum2(float a, float b, float* red) {
  const int tid = threadIdx.x;   // blockDim == 384
  __syncthreads();
  red[tid] = a; red[512 + tid] = b;
  if (tid < 128) { red[384 + tid] = 0.f; red[512 + 384 + tid] = 0.f; }
  __syncthreads();
  for (int s = 256; s > 0; s >>= 1) {
    if (tid < s) { red[tid] += red[tid + s]; red[512 + tid] += red[512 + tid + s]; }
    __syncthreads();
  }
  return make_float2(red[0], red[512]);
}

__global__ void small_mlp(
    const float* __restrict__ gc_mean, const float* __restrict__ qf,
    const int* __restrict__ mask,
    const float* __restrict__ gp_w1, const float* __restrict__ gp_b1,
    const float* __restrict__ gp_g1, const float* __restrict__ gp_be1,
    const float* __restrict__ gp_w2, const float* __restrict__ gp_b2,
    const float* __restrict__ swp_w1, const float* __restrict__ swp_b1,
    const float* __restrict__ swp_g1, const float* __restrict__ swp_be1,
    const float* __restrict__ swp_w2, const float* __restrict__ swp_b2,
    const float* __restrict__ swp_g2, const float* __restrict__ swp_be2,
    const float* __restrict__ swp_w3, const float* __restrict__ swp_b3,
    unsigned short* __restrict__ ctxs, unsigned short* __restrict__ ctxu,
    float* __restrict__ aw)
{
  __shared__ float gm[768];
  __shared__ float buf[832];
  __shared__ float tmp[384];
  __shared__ float red[1024];
  const int b = blockIdx.x, tid = threadIdx.x;

  for (int i = tid; i < 768; i += 384) gm[i] = gc_mean[b * 768 + i];
  __syncthreads();

  float z = gp_b1[tid];
  for (int k = 0; k < 768; k++) z += gm[k] * gp_w1[k * 384 + tid];
  float2 s = blk_sum2(z, z * z, red);
  {
    float mean = s.x * (1.f / 384.f);
    float rinv = rsqrtf(s.y * (1.f / 384.f) - mean * mean + 1e-5f);
    float y = (z - mean) * rinv * gp_g1[tid] + gp_be1[tid];
    tmp[tid] = fmaxf(y, 0.f);
  }
  __syncthreads();

  if (tid < 64) {
    float g = gp_b2[tid];
    for (int k = 0; k < 384; k++) g += tmp[k] * gp_w2[k * 64 + tid];
    float sc = (mask[b] != 0) ? 1.0f : 0.1f;
    ctxs[b * 64 + tid] = f2bf(g * sc);
    ctxu[b * 64 + tid] = f2bf(g);
    buf[tid] = g;
  }
  for (int i = tid; i < 768; i += 384) buf[64 + i] = qf[b * 768 + i];
  __syncthreads();

  float z1 = 0.f;
  if (tid < 256) {
    z1 = swp_b1[tid];
    for (int k = 0; k < 832; k++) z1 += buf[k] * swp_w1[k * 256 + tid];
  }
  s = blk_sum2(z1, z1 * z1, red);
  {
    float mean = s.x * (1.f / 256.f);
    float rinv = rsqrtf(s.y * (1.f / 256.f) - mean * mean + 1e-5f);
    if (tid < 256) {
      float y = (z1 - mean) * rinv * swp_g1[tid] + swp_be1[tid];
      tmp[tid] = 0.5f * y * (1.f + erff(y * 0.7071067811865476f));
    }
  }
  __syncthreads();

  float z2 = 0.f;
  if (tid < 128) {
    z2 = swp_b2[tid];
    for (int k = 0; k < 256; k++) z2 += tmp[k] * swp_w2[k * 128 + tid];
  }
  s = blk_sum2(z2, z2 * z2, red);
  {
    float mean = s.x * (1.f / 128.f);
    float rinv = rsqrtf(s.y * (1.f / 128.f) - mean * mean + 1e-5f);
    if (tid < 128) {
      float y = (z2 - mean) * rinv * swp_g2[tid] + swp_be2[tid];
      tmp[tid] = 0.5f * y * (1.f + erff(y * 0.7071067811865476f));
    }
  }
  __syncthreads();

  if (tid < 8) {
    float z3 = swp_b3[tid];
    for (int k = 0; k < 128; k++) z3 += tmp[k] * swp_w3[k * 8 + tid];
    buf[tid] = z3;
  }
  __syncthreads();
  if (tid < 8) {
    float mx = buf[0];
    for (int k = 1; k < 8; k++) mx = fmaxf(mx, buf[k]);
    float ssum = 0.f;
    for (int k = 0; k < 8; k++) ssum += expf(buf[k] - mx);
    aw[b * 8 + tid] = expf(buf[tid] - mx) / ssum;
  }
}

// ---------------------------------------------------------------- stats
__global__ void stats_k(const float2* __restrict__ part, float2* __restrict__ st,
                        int nr) {
  int i = blockIdx.x * 256 + threadIdx.x;
  if (i >= nr) return;
  float2 p0 = part[i], p1 = part[nr + i], p2 = part[2 * nr + i];
  float s1 = p0.x + p1.x + p2.x, s2 = p0.y + p1.y + p2.y;
  float mean = s1 * (1.f / 768.f);
  float var = s2 * (1.f / 768.f) - mean * mean;
  float rinv = rsqrtf(var + 1e-5f);
  st[i] = make_float2(rinv, -mean * rinv);
}

// ================================================================ GEMM1
// 128x256xK832, 8 waves (2m x 4n, wave-tile 64x64), 2-slot ring,
// commit-after-compute (T14 write-late). Targets <=128 total regs -> 4 w/SIMD.
__global__ __launch_bounds__(512, 4)
void gemm1_k(const float* __restrict__ comps,
             const unsigned short* __restrict__ cxs,
             const unsigned short* __restrict__ cxu,
             const unsigned short* __restrict__ w1T,
             const float* __restrict__ sb1, const float* __restrict__ rb1,
             unsigned short* __restrict__ z1,
             float2* __restrict__ part1,
             const int* __restrict__ mask)
{
  __shared__ __align__(16) unsigned short As[2][4096];
  __shared__ __align__(16) unsigned short Bs[2][8192];
  __shared__ float pscr[4][128][2];
  constexpr int NT = 26;

  const int id = blockIdx.x;
  const int x = id & 7, j = id >> 3;        // x = XCD stream
  const int br_nt = j >> 4;                 // 0..23
  const int mt = ((j & 15) << 3) | x;       // 0..127
  const int nt = br_nt % 3;
  const int br = br_nt / 3;                 // 0..7
  const int m0 = mt * 128, n0 = nt * 256;
  const int b = m0 >> 10;
  if (br >= 5 && mask[b] == 0) return;

  const int ci = (0x76245310u >> (br * 4)) & 15;
  const float* afp = comps + (size_t)ci * MT * DD + (size_t)m0 * DD;
  const unsigned short* ctxp = ((br <= 4) ? cxs : cxu) + b * 64;
  const unsigned short* wT = w1T + (size_t)br * DD * 832 + (size_t)n0 * 832;

  const int tid = threadIdx.x;
  const int w = tid >> 6, lane = tid & 63, llo = lane & 15, lhi = lane >> 4;
  const int wm = w & 1, wn = w >> 1;

  // A staging: 1 slot (16B) per thread; write-side swizzle
  const int arow = tid >> 2, ap = tid & 3;
  const int aslot = (arow * 32 + ((ap ^ ((arow >> 1) & 3)) << 3));
  const float* asrc = afp + (size_t)arow * DD + ap * 8;
  const unsigned short* csrc = ctxp + ap * 8;

  // B staging: 2 DMAs per wave, pre-swizzled source
  const int q = lane & 3, rrB = w * 16 + (lane >> 2);
  const int swqB = q ^ ((rrB >> 1) & 3);
  const unsigned short* bsrc0 = wT + (size_t)rrB * 832 + swqB * 8;
  const unsigned short* bsrc1 = wT + (size_t)(128 + rrB) * 832 + swqB * 8;

  f32x4 acc[4][4];
#pragma unroll
  for (int mf = 0; mf < 4; ++mf)
#pragma unroll
    for (int nf = 0; nf < 4; ++nf) acc[mf][nf] = (f32x4)0.0f;

  struct St { u32x4 q0, q1; };

  auto issueB = [&](int kt, int s) {
    gload_lds16(bsrc0 + (size_t)kt * 32, &Bs[s][w * 512]);
    gload_lds16(bsrc1 + (size_t)kt * 32, &Bs[s][4096 + w * 512]);
  };
  auto loadA = [&](int kt) -> St {
    St s;
    if (kt < 24) {
      const u32x4* p = (const u32x4*)(asrc + kt * 32);
      s.q0 = p[0]; s.q1 = p[1];
    } else {
      s.q0 = *(const u32x4*)(csrc + (kt - 24) * 32);
      s.q1 = s.q0;
    }
    return s;
  };
  auto commitA = [&](const St& s, int kt, int sl) {
    u32x4 v;
    if (kt < 24) {
      v[0] = pk2(__uint_as_float(s.q0[0]), __uint_as_float(s.q0[1]));
      v[1] = pk2(__uint_as_float(s.q0[2]), __uint_as_float(s.q0[3]));
      v[2] = pk2(__uint_as_float(s.q1[0]), __uint_as_float(s.q1[1]));
      v[3] = pk2(__uint_as_float(s.q1[2]), __uint_as_float(s.q1[3]));
    } else {
      v = s.q0;
    }
    *(u32x4*)&As[sl][aslot] = v;
  };

  const int aswz = (lhi ^ ((llo >> 1) & 3)) << 3;
  const int arow0 = (wm * 64 + llo) * 32 + aswz;
  const int brow0 = (wn * 64 + llo) * 32 + aswz;
  auto compute = [&](int sl) {
    short8 afr[4];
#pragma unroll
    for (int mf = 0; mf < 4; ++mf)
      afr[mf] = *(const short8*)&As[sl][arow0 + mf * 512];
#pragma unroll
    for (int nf = 0; nf < 4; ++nf) {
      short8 bfr = *(const short8*)&Bs[sl][brow0 + nf * 512];
#pragma unroll
      for (int mf = 0; mf < 4; ++mf)
        acc[mf][nf] = __builtin_amdgcn_mfma_f32_16x16x32_bf16(afr[mf], bfr, acc[mf][nf], 0, 0, 0);
    }
  };

  // prologue
  issueB(0, 0);
  {
    St s0 = loadA(0);
    commitA(s0, 0, 0);
  }
  asm volatile("s_waitcnt lgkmcnt(0)" ::: "memory");
  __builtin_amdgcn_sched_barrier(0);
  __builtin_amdgcn_s_barrier();

#pragma unroll 1
  for (int t = 0; t < NT; ++t) {
    const int cur = t & 1, nxt = cur ^ 1;
    const bool more = (t + 1 < NT);
    St sn;
    if (more) {
      issueB(t + 1, nxt);               // DMA in flight under MFMA
      sn = loadA(t + 1);                // global->reg, lands under MFMA
    }
    __builtin_amdgcn_sched_barrier(0);  // pin issues before compute
    compute(cur);
    __builtin_amdgcn_sched_barrier(0);  // pin commit after compute (T14)
    if (more) commitA(sn, t + 1, nxt);  // auto-vmcnt: also retires B(t+1)
    asm volatile("s_waitcnt lgkmcnt(0)" ::: "memory");
    __builtin_amdgcn_sched_barrier(0);
    __builtin_amdgcn_s_barrier();
  }

  // epilogue
  const float* bias = ((br < 4) ? sb1 : rb1) + (br & 3) * DD;
  unsigned short* zo = z1 + (size_t)br * MT * DD + (size_t)m0 * DD;
  const int n0w = n0 + wn * 64;
  float bia[4];
#pragma unroll
  for (int nf = 0; nf < 4; ++nf) bia[nf] = bias[n0w + nf * 16 + llo];
#pragma unroll
  for (int mf = 0; mf < 4; ++mf) {
#pragma unroll
    for (int r = 0; r < 4; ++r) {
      float zz[4]; float s1v = 0.f, s2v = 0.f;
#pragma unroll
      for (int nf = 0; nf < 4; ++nf) {
        float zv = acc[mf][nf][r] + bia[nf];
        zz[nf] = zv; s1v += zv; s2v += zv * zv;
      }
      const int rloc = wm * 64 + mf * 16 + lhi * 4 + r;
      const size_t rowoff = (size_t)rloc * DD;
#pragma unroll
      for (int nf = 0; nf < 4; ++nf) {
        float zon = __shfl_xor(zz[nf], 1);
        if ((llo & 1) == 0)
          *(unsigned*)&zo[rowoff + n0w + nf * 16 + llo] = pk2(zz[nf], zon);
      }
#pragma unroll
      for (int d = 1; d < 16; d <<= 1) {
        s1v += __shfl_xor(s1v, d); s2v += __shfl_xor(s2v, d);
      }
      if (llo == 0) { pscr[wn][rloc][0] = s1v; pscr[wn][rloc][1] = s2v; }
    }
  }
  __syncthreads();
  if (tid < 128) {
    float a = 0.f, c = 0.f;
#pragma unroll
    for (int qq = 0; qq < 4; ++qq) { a += pscr[qq][tid][0]; c += pscr[qq][tid][1]; }
    part1[(size_t)nt * (8 * MT) + (size_t)br * MT + m0 + tid] = make_float2(a, c);
  }
}

// ---------------------------------------------------------------- act1
// a1 = act(ln(z1)) bf16 -- removes the transform from gemm2's K-loop.
__global__ void act1_k(const unsigned short* __restrict__ z1,
                       const float2* __restrict__ st1,
                       const float* __restrict__ sg1, const float* __restrict__ sbe1,
                       const float* __restrict__ rg1, const float* __restrict__ rbe1,
                       const int* __restrict__ mask,
                       unsigned short* __restrict__ a1)
{
  const int tid = threadIdx.x;
  const int rowg = blockIdx.x * 8 + (tid >> 5);   // 0..131071
  const int l = tid & 31;
  const int br = rowg >> 14;
  const int r = rowg & 16383;
  const int b = r >> 10;
  if (br >= 5 && mask[b] == 0) return;
  const bool isg = (br < 4);
  const float* g  = (isg ? sg1  + br * DD : rg1  + (br - 4) * DD);
  const float* be = (isg ? sbe1 + br * DD : rbe1 + (br - 4) * DD);
  const float2 stv = st1[rowg];
  const unsigned short* zp = z1 + (size_t)rowg * DD;
  unsigned short* op = a1 + (size_t)rowg * DD;
#pragma unroll
  for (int c = 0; c < 3; ++c) {
    const int col = l * 8 + c * 256;
    u32x4 zv = *(const u32x4*)(zp + col);
    fv4 ga = *(const fv4*)(g + col), gb = *(const fv4*)(g + col + 4);
    fv4 ba = *(const fv4*)(be + col), bb = *(const fv4*)(be + col + 4);
    float y[8];
#pragma unroll
    for (int wd = 0; wd < 2; ++wd) {
      y[2*wd]   = fmaf(fmaf(bf2f((unsigned short)(zv[wd] & 0xffffu)), stv.x, stv.y), ga[2*wd], ba[2*wd]);
      y[2*wd+1] = fmaf(fmaf(bf2f((unsigned short)(zv[wd] >> 16)), stv.x, stv.y), ga[2*wd+1], ba[2*wd+1]);
      y[4+2*wd]   = fmaf(fmaf(bf2f((unsigned short)(zv[wd+2] & 0xffffu)), stv.x, stv.y), gb[2*wd], bb[2*wd]);
      y[4+2*wd+1] = fmaf(fmaf(bf2f((unsigned short)(zv[wd+2] >> 16)), stv.x, stv.y), gb[2*wd+1], bb[2*wd+1]);
    }
    u32x4 ov;
#pragma unroll
    for (int wd = 0; wd < 4; ++wd) {
      float y0 = y[2*wd], y1 = y[2*wd+1];
      if (isg) { y0 = gelu_t(y0); y1 = gelu_t(y1); }
      else     { y0 = fmaxf(y0, 0.f); y1 = fmaxf(y1, 0.f); }
      ov[wd] = pk2(y0, y1);
    }
    *(u32x4*)(op + col) = ov;
  }
}

// ================================================================ GEMM2
// 128x256xK768, pure-DMA both operands, 3-slot ring, counted vmcnt(3) (T4).
// br<4: out z2 bf16 + partials; br>=4: fp32 out (masked k>=1 -> copy comps).
__global__ __launch_bounds__(512, 4)
void gemm2_k(const float* __restrict__ comps,
             const unsigned short* __restrict__ a1,
             const unsigned short* __restrict__ w2T,
             const float* __restrict__ sb2, const float* __restrict__ rb2,
             unsigned short* __restrict__ z2,
             float2* __restrict__ part2,
             float* __restrict__ outp,
             const int* __restrict__ mask)
{
  __shared__ __align__(16) unsigned short As[3][4096];
  __shared__ __align__(16) unsigned short Bs[3][8192];
  __shared__ float pscr[4][128][2];
  constexpr int NT = 24;

  const int id = blockIdx.x;
  const int x = id & 7, j = id >> 3;
  const int br_nt = j >> 4;                 // 0..23
  const int mt = ((j & 15) << 3) | x;       // 0..127
  const int nt = br_nt % 3;
  const int br = br_nt / 3;
  const int m0 = mt * 128, n0 = nt * 256;
  const int b = m0 >> 10;
  const int ci = (0x76245310u >> (br * 4)) & 15;
  const int tid = threadIdx.x;

  if (br >= 5 && mask[b] == 0) {            // masked: out = comps
    const float* cs = comps + (size_t)ci * MT * DD + (size_t)m0 * DD + n0;
    float* cd = outp + (size_t)ci * MT * DD + (size_t)m0 * DD + n0;
#pragma unroll 1
    for (int k = 0; k < 16; ++k) {
      int idx = tid + k * 512;
      int r2 = idx >> 6, c4 = (idx & 63) * 4;
      *(fv4*)(cd + (size_t)r2 * DD + c4) = *(const fv4*)(cs + (size_t)r2 * DD + c4);
    }
    return;
  }

  const unsigned short* az = a1 + (size_t)br * MT * DD + (size_t)m0 * DD;
  const unsigned short* wT = w2T + (size_t)br * DD * DD + (size_t)n0 * DD;

  const int w = tid >> 6, lane = tid & 63, llo = lane & 15, lhi = lane >> 4;
  const int wm = w & 1, wn = w >> 1;
  const int q = lane & 3, rrB = w * 16 + (lane >> 2);
  const int swqB = q ^ ((rrB >> 1) & 3);

  const unsigned short* asrcD = az + (size_t)rrB * DD + swqB * 8;
  const unsigned short* bsrc0 = wT + (size_t)rrB * DD + swqB * 8;
  const unsigned short* bsrc1 = wT + (size_t)(128 + rrB) * DD + swqB * 8;

  f32x4 acc[4][4];
#pragma unroll
  for (int mf = 0; mf < 4; ++mf)
#pragma unroll
    for (int nf = 0; nf < 4; ++nf) acc[mf][nf] = (f32x4)0.0f;

  auto issueT = [&](int kt, int s) {        // 3 DMAs per wave per tile
    gload_lds16(asrcD + (size_t)kt * 32, &As[s][w * 512]);
    gload_lds16(bsrc0 + (size_t)kt * 32, &Bs[s][w * 512]);
    gload_lds16(bsrc1 + (size_t)kt * 32, &Bs[s][4096 + w * 512]);
  };

  const int aswz = (lhi ^ ((llo >> 1) & 3)) << 3;
  const int arow0 = (wm * 64 + llo) * 32 + aswz;
  const int brow0 = (wn * 64 + llo) * 32 + aswz;
  auto compute = [&](int sl) {
    short8 afr[4];
#pragma unroll
    for (int mf = 0; mf < 4; ++mf)
      afr[mf] = *(const short8*)&As[sl][arow0 + mf * 512];
#pragma unroll
    for (int nf = 0; nf < 4; ++nf) {
      short8 bfr = *(const short8*)&Bs[sl][brow0 + nf * 512];
#pragma unroll
      for (int mf = 0; mf < 4; ++mf)
        acc[mf][nf] = __builtin_amdgcn_mfma_f32_16x16x32_bf16(afr[mf], bfr, acc[mf][nf], 0, 0, 0);
    }
  };

  // prologue: tiles 0,1 in flight; wait tile 0 only
  issueT(0, 0);
  issueT(1, 1);
  asm volatile("s_waitcnt vmcnt(3)" ::: "memory");
  __builtin_amdgcn_sched_barrier(0);
  __builtin_amdgcn_s_barrier();

  int sl = 0;
#pragma unroll 1
  for (int t = 0; t < NT; ++t) {
    int sl2 = sl + 2; if (sl2 >= 3) sl2 -= 3;
    const bool more = (t + 2 < NT);
    if (more) issueT(t + 2, sl2);
    __builtin_amdgcn_sched_barrier(0);
    compute(sl);
    if (more) asm volatile("s_waitcnt vmcnt(3)" ::: "memory");
    else      asm volatile("s_waitcnt vmcnt(0)" ::: "memory");
    asm volatile("s_waitcnt lgkmcnt(0)" ::: "memory");
    __builtin_amdgcn_sched_barrier(0);
    __builtin_amdgcn_s_barrier();
    ++sl; if (sl == 3) sl = 0;
  }

  // epilogue
  const int n0w = n0 + wn * 64;
  const float* bias = ((br < 4) ? sb2 : rb2) + (br & 3) * DD;
  float bia[4];
#pragma unroll
  for (int nf = 0; nf < 4; ++nf) bia[nf] = bias[n0w + nf * 16 + llo];

  if (br < 4) {
    unsigned short* zo = z2 + (size_t)br * MT * DD + (size_t)m0 * DD;
#pragma unroll
    for (int mf = 0; mf < 4; ++mf) {
#pragma unroll
      for (int r = 0; r < 4; ++r) {
        float zz[4]; float s1v = 0.f, s2v = 0.f;
#pragma unroll
        for (int nf = 0; nf < 4; ++nf) {
          float zv = acc[mf][nf][r] + bia[nf];
          zz[nf] = zv; s1v += zv; s2v += zv * zv;
        }
        const int rloc = wm * 64 + mf * 16 + lhi * 4 + r;
        const size_t rowoff = (size_t)rloc * DD;
#pragma unroll
        for (int nf = 0; nf < 4; ++nf) {
          float zon = __shfl_xor(zz[nf], 1);
          if ((llo & 1) == 0)
            *(unsigned*)&zo[rowoff + n0w + nf * 16 + llo] = pk2(zz[nf], zon);
        }
#pragma unroll
        for (int d = 1; d < 16; d <<= 1) {
          s1v += __shfl_xor(s1v, d); s2v += __shfl_xor(s2v, d);
        }
        if (llo == 0) { pscr[wn][rloc][0] = s1v; pscr[wn][rloc][1] = s2v; }
      }
    }
    __syncthreads();
    if (tid < 128) {
      float a = 0.f, c = 0.f;
#pragma unroll
      for (int qq = 0; qq < 4; ++qq) { a += pscr[qq][tid][0]; c += pscr[qq][tid][1]; }
      part2[(size_t)nt * (4 * MT) + (size_t)br * MT + m0 + tid] = make_float2(a, c);
    }
  } else {
    float* fo = outp + (size_t)ci * MT * DD + (size_t)m0 * DD;
#pragma unroll
    for (int mf = 0; mf < 4; ++mf) {
#pragma unroll
      for (int r = 0; r < 4; ++r) {
        const int rloc = wm * 64 + mf * 16 + lhi * 4 + r;
        const size_t rowoff = (size_t)rloc * DD;
#pragma unroll
        for (int nf = 0; nf < 4; ++nf)
          fo[rowoff + n0w + nf * 16 + llo] = acc[mf][nf][r] + bia[nf];
      }
    }
  }
}

// ---------------------------------------------------------------- finish s
__global__ void finish_s(const unsigned short* __restrict__ z2,
                         const float2* __restrict__ st2,
                         const float* __restrict__ sg2,
                         const float* __restrict__ sbe2,
                         float* __restrict__ outp)
{
  const int tid = threadIdx.x;
  const int rowg = blockIdx.x * 8 + (tid >> 5);     // 0..65535
  const int l = tid & 31;
  const int br = rowg >> 14;
  const int r = rowg & 16383;
  const int ci = (0x5310u >> (br * 4)) & 15;
  const unsigned short* zp = z2 + (size_t)rowg * DD;
  float* op = outp + (size_t)ci * MT * DD + (size_t)r * DD;
  const float2 stv = st2[rowg];
  const float* g = sg2 + br * DD;
  const float* be = sbe2 + br * DD;
#pragma unroll
  for (int c = 0; c < 3; ++c) {
    const int col = l * 8 + c * 256;
    u32x4 zv = *(const u32x4*)(zp + col);
    fv4 ga = *(const fv4*)(g + col), gb = *(const fv4*)(g + col + 4);
    fv4 ba = *(const fv4*)(be + col), bb = *(const fv4*)(be + col + 4);
    fv4 o0, o1;
#pragma unroll
    for (int wd = 0; wd < 2; ++wd) {
      o0[2 * wd]     = fmaf(fmaf(bf2f((unsigned short)(zv[wd] & 0xffffu)), stv.x, stv.y), ga[2 * wd], ba[2 * wd]);
      o0[2 * wd + 1] = fmaf(fmaf(bf2f((unsigned short)(zv[wd] >> 16)), stv.x, stv.y), ga[2 * wd + 1], ba[2 * wd + 1]);
      o1[2 * wd]     = fmaf(fmaf(bf2f((unsigned short)(zv[wd + 2] & 0xffffu)), stv.x, stv.y), gb[2 * wd], bb[2 * wd]);
      o1[2 * wd + 1] = fmaf(fmaf(bf2f((unsigned short)(zv[wd + 2] >> 16)), stv.x, stv.y), gb[2 * wd + 1], bb[2 * wd + 1]);
    }
    *(fv4*)(op + col) = o0;
    *(fv4*)(op + col + 4) = o1;
  }
}

// ---------------------------------------------------------------- launch
extern "C" void kernel_launch(void* const* d_in, const int* in_sizes, int n_in,
                              void* d_out, int out_size, void* d_ws, size_t ws_size,
                              hipStream_t stream)
{
  (void)in_sizes; (void)n_in; (void)out_size; (void)ws_size;
  const float* comps  = (const float*)d_in[0];
  const float* geo    = (const float*)d_in[1];
  const float* qf     = (const float*)d_in[2];
  const int*   mask   = (const int*)d_in[3];
  const float* gp_w1  = (const float*)d_in[4];
  const float* gp_b1  = (const float*)d_in[5];
  const float* gp_g1  = (const float*)d_in[6];
  const float* gp_be1 = (const float*)d_in[7];
  const float* gp_w2  = (const float*)d_in[8];
  const float* gp_b2  = (const float*)d_in[9];
  const float* swp_w1 = (const float*)d_in[10];
  const float* swp_b1 = (const float*)d_in[11];
  const float* swp_g1 = (const float*)d_in[12];
  const float* swp_be1= (const float*)d_in[13];
  const float* swp_w2 = (const float*)d_in[14];
  const float* swp_b2 = (const float*)d_in[15];
  const float* swp_g2 = (const float*)d_in[16];
  const float* swp_be2= (const float*)d_in[17];
  const float* swp_w3 = (const float*)d_in[18];
  const float* swp_b3 = (const float*)d_in[19];
  const float* sw1 = (const float*)d_in[20];
  const float* sb1 = (const float*)d_in[21];
  const float* sg1 = (const float*)d_in[22];
  const float* sbe1= (const float*)d_in[23];
  const float* sw2 = (const float*)d_in[24];
  const float* sb2 = (const float*)d_in[25];
  const float* sg2 = (const float*)d_in[26];
  const float* sbe2= (const float*)d_in[27];
  const float* rw1 = (const float*)d_in[28];
  const float* rb1 = (const float*)d_in[29];
  const float* rg1 = (const float*)d_in[30];
  const float* rbe1= (const float*)d_in[31];
  const float* rw2 = (const float*)d_in[32];
  const float* rb2 = (const float*)d_in[33];
  float* out = (float*)d_out;

  char* ws = (char*)d_ws;
  unsigned short* w1T = (unsigned short*)(ws + OFF_W1T);
  unsigned short* w2T = (unsigned short*)(ws + OFF_W2T);
  unsigned short* z1  = (unsigned short*)(ws + OFF_Z1);
  unsigned short* z2  = (unsigned short*)(ws + OFF_Z2);
  float2* part1 = (float2*)(ws + OFF_P1);
  float2* part2 = (float2*)(ws + OFF_P2);
  float2* st1   = (float2*)(ws + OFF_ST1);
  float2* st2   = (float2*)(ws + OFF_ST2);
  float* gpart  = (float*)(ws + OFF_GP);
  float* gmean  = (float*)(ws + OFF_GM);
  unsigned short* cxs = (unsigned short*)(ws + OFF_CXS);
  unsigned short* cxu = (unsigned short*)(ws + OFF_CXU);
  unsigned short* a1  = (unsigned short*)(ws + OFF_A1);

  transpose_cvt<<<dim3(26, 24, 16), 256, 0, stream>>>(sw1, rw1, sw2, rw2, w1T, w2T);
  colmean1<<<dim3(3, 8, 16), 256, 0, stream>>>(geo, gpart);
  colmean2<<<dim3(3, 16), 256, 0, stream>>>(gpart, gmean);
  small_mlp<<<16, 384, 0, stream>>>(gmean, qf, mask,
      gp_w1, gp_b1, gp_g1, gp_be1, gp_w2, gp_b2,
      swp_w1, swp_b1, swp_g1, swp_be1, swp_w2, swp_b2, swp_g2, swp_be2,
      swp_w3, swp_b3, cxs, cxu, out + AW_OFF);

  gemm1_k<<<3072, 512, 0, stream>>>(comps, cxs, cxu, w1T, sb1, rb1, z1, part1, mask);
  stats_k<<<512, 256, 0, stream>>>(part1, st1, 8 * MT);
  act1_k<<<16384, 256, 0, stream>>>(z1, st1, sg1, sbe1, rg1, rbe1, mask, a1);
  gemm2_k<<<3072, 512, 0, stream>>>(comps, a1, w2T, sb2, rb2, z2, part2, out, mask);
  stats_k<<<256, 256, 0, stream>>>(part2, st2, 4 * MT);
  finish_s<<<8192, 256, 0, stream>>>(z2, st2, sg2, sbe2, out);
}